// Round 12
// baseline (1108.180 us; speedup 1.0000x reference)
//
#include <hip/hip_runtime.h>
#include <cstdint>

typedef unsigned short ushort_t;
typedef __bf16 bf16x8 __attribute__((ext_vector_type(8)));
typedef float f32x4 __attribute__((ext_vector_type(4)));
typedef ushort_t us8 __attribute__((ext_vector_type(8)));
typedef unsigned int u32x4 __attribute__((ext_vector_type(4)));

// ---------- helpers ----------
__device__ __forceinline__ ushort_t f2bf(float f) {
  union { float f; unsigned int u; } v; v.f = f;
  unsigned int u = v.u;
  unsigned int r = (u + 0x7fffu + ((u >> 16) & 1u)) >> 16;
  return (ushort_t)r;
}
__device__ __forceinline__ float bf2f(ushort_t u) {
  union { unsigned int u; float f; } v; v.u = ((unsigned int)u) << 16; return v.f;
}

// EPI: 0 = outf = acc + bias                     (out)
//      8 = outb = bf16(acc + bias)               (logits)
//      1 = outb = bf16(acc+bias); outb2 = bf16(relu^2)    (H1b + H2b)
//      2 = outb = bf16(acc * 2*sqrt(auxb))       (g1)
//      4 = outb = bf16(relu(bf2f(auxb) - ss0*acc)^2); K-limit  (x2)
//      5 = outf = auxf - ss2*acc; K-limit        (x3)
//      6 = split-K partial, full-matrix f32      (H3, G4, X3 stage 1)
//      7 = split-K partial, compact-tri grid, 128x128 tiles   (S1, S2 stage 1)
struct GemmP {
  const ushort_t* A; const ushort_t* B;
  int M, N, K;
  long long sA, sB;
  float* outf;   long long sOutF;
  ushort_t* outb; long long sOutB;
  ushort_t* outb2;
  const float* bias;
  const float* auxf; long long sAuxF;   // sAuxF doubles as aux (f32 or bf16) stride
  const ushort_t* auxb;
  const float* steps;
  float* part; int ksplit, Kc, Tt;
};

// R11 falsification: READ BW pinned at ~1.2 TB/s across 6 schedules x 3 occupancy
// configs, all staging via global_load_lds; the R10 spill kernel (plain VMEM)
// sustained 5.15 TB/s. Theory: the gload_lds LDS-DMA path allows only ~2
// outstanding requests/CU -> HBM-cold reads cap at ~1.2 TB/s. Fix (T14 / HK
// pattern): REGISTER staging. Per-lane global_load_dwordx4 -> VGPR -> ds_write
// to the SAME linear layout (lane*16B), so ds_read offsets + T2 swizzle are
// unchanged. Even/odd staging reg sets, unroll-by-2 loop, one barrier/phase:
//   {compute(buf); ds_write tile t+1 from regs; issue loads tile t+2;
//    lgkmcnt(0); barrier}
// Loads stay in flight across phases; in-flight bytes now scale with waves.

#define LOADT_BT(t, S)                                                        \
  { const int kk_ = kbeg + (t) * 32;                                          \
    rA0##S = *(const u32x4*)(gA0 + kk_); rA1##S = *(const u32x4*)(gA1 + kk_); \
    rB0##S = *(const u32x4*)(gB0 + kk_); rB1##S = *(const u32x4*)(gB1 + kk_); }
#define STORET_BT(o, S)                                                       \
  { *(u32x4*)(wA0 + (o)) = rA0##S; *(u32x4*)(wA1 + (o)) = rA1##S;             \
    *(u32x4*)(wB0 + (o)) = rB0##S; *(u32x4*)(wB1 + (o)) = rB1##S; }
#define PHASE_END()                                                           \
  { asm volatile("s_waitcnt lgkmcnt(0)" ::: "memory");                        \
    __builtin_amdgcn_sched_barrier(0);                                        \
    __builtin_amdgcn_s_barrier(); }

// ---------- 128x128 GEMM: 4 waves, BK=32, 2x16KB buffers, reg-staged ----------
template <int EPI>
__global__ __launch_bounds__(256) void gemm_bt(GemmP p) {
  const int nwg = gridDim.x * gridDim.y;
  const int orig = blockIdx.y * gridDim.x + blockIdx.x;
  const int xcd = orig & 7, loc = orig >> 3;
  const int q8 = nwg >> 3, r8 = nwg & 7;
  const int wg = (xcd < r8) ? (xcd * (q8 + 1) + loc) : (r8 * (q8 + 1) + (xcd - r8) * q8 + loc);
  int mt, nt;
  if (EPI == 7) {            // compact lower-tri tile index -> (mt, nt)
    int t_ = wg;
    mt = (int)((sqrtf(8.f * t_ + 1.f) - 1.f) * 0.5f);
    while ((mt + 1) * (mt + 2) / 2 <= t_) mt++;
    while (mt * (mt + 1) / 2 > t_) mt--;
    nt = t_ - mt * (mt + 1) / 2;
  } else {
    nt = wg % gridDim.x; mt = wg / gridDim.x;
  }
  const int m0 = mt * 128, n0 = nt * 128;

  int bz = blockIdx.z, ks = 0;
  if (EPI == 6 || EPI == 7) { bz = blockIdx.z / p.ksplit; ks = blockIdx.z % p.ksplit; }

  const ushort_t* A = p.A + (size_t)bz * p.sA;
  const ushort_t* B = p.B + (size_t)bz * p.sB;

  int kbeg = 0, kend = p.K;
  if (EPI == 6 || EPI == 7) { kbeg = ks * p.Kc; kend = kbeg + p.Kc; }
  else if (EPI == 4 || EPI == 5) kend = min(p.K, m0 + 128);

  __shared__ ushort_t sA[2 * 128 * 32];   // 16KB
  __shared__ ushort_t sB[2 * 128 * 32];   // 16KB -> 32KB total

  const int tid = threadIdx.x;
  const int wid = tid >> 6, lane = tid & 63;
  const int wm = wid >> 1, wn = wid & 1;

  f32x4 acc[4][4];
#pragma unroll
  for (int i = 0; i < 4; i++)
#pragma unroll
    for (int j = 0; j < 4; j++) acc[i][j] = f32x4{0.f, 0.f, 0.f, 0.f};

  // staging: chunk = 16 rows x 32 cols = 1KB; wave w stages A/B chunks {w, w+4}.
  // Global source col pre-swizzled (T2); LDS dest linear (lane*16B) -> layout
  // identical to the old gload_lds path; ds_read offsets unchanged.
  const int lr = lane >> 2;
  const int lcsw = (((lane & 3) ^ ((lr >> 1) & 3)) * 8);
  const int rA0r = wid * 16 + lr;
  const int rA1r = 64 + wid * 16 + lr;
  const ushort_t* gA0 = A + (size_t)(m0 + rA0r) * p.K + lcsw;
  const ushort_t* gA1 = A + (size_t)(m0 + rA1r) * p.K + lcsw;
  const ushort_t* gB0 = B + (size_t)(n0 + rA0r) * p.K + lcsw;
  const ushort_t* gB1 = B + (size_t)(n0 + rA1r) * p.K + lcsw;
  ushort_t* wA0 = &sA[wid * 512 + lane * 8];
  ushort_t* wA1 = &sA[(4 + wid) * 512 + lane * 8];
  ushort_t* wB0 = &sB[wid * 512 + lane * 8];
  ushort_t* wB1 = &sB[(4 + wid) * 512 + lane * 8];

  // swizzled ds_read offsets (loop-invariant)
  const int fr = lane & 15;
  const int q = lane >> 4;
  const int slot = (q ^ ((fr >> 1) & 3)) * 8;
  int offA[4], offB[4];
#pragma unroll
  for (int i = 0; i < 4; i++) offA[i] = (wm * 4 + i) * 512 + fr * 32 + slot;
#pragma unroll
  for (int j = 0; j < 4; j++) offB[j] = (wn * 4 + j) * 512 + fr * 32 + slot;

  const int nT = (kend - kbeg) >> 5;    // BK = 32
  u32x4 rA0e, rA1e, rB0e, rB1e;         // even-tile staging regs
  u32x4 rA0o, rA1o, rB0o, rB1o;         // odd-tile staging regs

  auto compute = [&](int co) {
    bf16x8 av[4], bv[4];
#pragma unroll
    for (int j = 0; j < 4; j++) bv[j] = *reinterpret_cast<const bf16x8*>(&sB[co + offB[j]]);
#pragma unroll
    for (int i = 0; i < 4; i++) av[i] = *reinterpret_cast<const bf16x8*>(&sA[co + offA[i]]);
    __builtin_amdgcn_s_setprio(1);
#pragma unroll
    for (int i = 0; i < 4; i++)
#pragma unroll
      for (int j = 0; j < 4; j++)
        acc[i][j] = __builtin_amdgcn_mfma_f32_16x16x32_bf16(av[i], bv[j], acc[i][j], 0, 0, 0);
    __builtin_amdgcn_s_setprio(0);
  };

  LOADT_BT(0, e);
  STORET_BT(0, e);
  if (nT > 1) LOADT_BT(1, o);
  PHASE_END();

  for (int t = 0; t < nT; t += 2) {
    // even phase: compute tile t (buf0); publish t+1; issue t+2
    compute(0);
    if (t + 1 < nT) STORET_BT(4096, o);
    if (t + 2 < nT) LOADT_BT(t + 2, e);
    PHASE_END();
    if (t + 1 < nT) {
      // odd phase: compute tile t+1 (buf1); publish t+2; issue t+3
      compute(4096);
      if (t + 2 < nT) STORET_BT(0, e);
      if (t + 3 < nT) LOADT_BT(t + 3, o);
      PHASE_END();
    }
  }

  const int fq = q;
  float ss = 0.f;
  if (EPI == 4) ss = p.steps[0];
  else if (EPI == 5) ss = p.steps[2];
  float* outf = p.outf ? p.outf + (size_t)bz * p.sOutF : nullptr;
  ushort_t* outb = p.outb ? p.outb + (size_t)bz * p.sOutB : nullptr;
  ushort_t* outb2 = p.outb2;
  const float* auxf = p.auxf ? p.auxf + (size_t)bz * p.sAuxF : nullptr;
  const ushort_t* auxb = p.auxb ? p.auxb + (size_t)bz * p.sAuxF : nullptr;
  float* partT = nullptr;
  if (EPI == 6) partT = p.part + (size_t)blockIdx.z * p.M * p.N;
  if (EPI == 7) partT = p.part + ((size_t)blockIdx.z * p.Tt + wg) * 16384;

#pragma unroll
  for (int i = 0; i < 4; i++) {
#pragma unroll
    for (int j = 0; j < 4; j++) {
#pragma unroll
      for (int r2 = 0; r2 < 4; r2++) {
        int lrow = wm * 64 + i * 16 + fq * 4 + r2;
        int lcol = wn * 64 + j * 16 + fr;
        int row = m0 + lrow, col = n0 + lcol;
        size_t g = (size_t)row * p.N + col;
        float v = acc[i][j][r2];
        if (EPI == 0) {
          outf[g] = v + (p.bias ? p.bias[col] : 0.f);
        } else if (EPI == 8) {
          outb[g] = f2bf(v + p.bias[col]);
        } else if (EPI == 1) {
          v += p.bias[col];
          outb[g] = f2bf(v);
          float rl = fmaxf(v, 0.f);
          outb2[g] = f2bf(rl * rl);
        } else if (EPI == 2) {
          outb[g] = f2bf(v * 2.f * sqrtf(bf2f(auxb[g])));
        } else if (EPI == 4) {
          float x1 = bf2f(auxb[g]) - ss * v;
          float rl = fmaxf(x1, 0.f);
          outb[g] = f2bf(rl * rl);
        } else if (EPI == 5) {
          outf[g] = auxf[g] - ss * v;
        } else if (EPI == 6) {
          partT[g] = v;
        } else if (EPI == 7) {
          partT[lrow * 128 + lcol] = v;
        }
      }
    }
  }
}

// ---------- 256x256 GEMM: 8 waves, BK=32, 2x32KB buffers, reg-staged ----------
// Used for the big class-B GEMMs (logits, out).
template <int EPI>
__global__ __launch_bounds__(512) void gemm256(GemmP p) {
  const int nwg = gridDim.x * gridDim.y;
  const int orig = blockIdx.y * gridDim.x + blockIdx.x;
  const int xcd = orig & 7, loc = orig >> 3;
  const int q8 = nwg >> 3, r8 = nwg & 7;
  const int wg = (xcd < r8) ? (xcd * (q8 + 1) + loc) : (r8 * (q8 + 1) + (xcd - r8) * q8 + loc);
  const int nt = wg % gridDim.x, mt = wg / gridDim.x;
  const int m0 = mt * 256, n0 = nt * 256;

  const ushort_t* A = p.A;
  const ushort_t* B = p.B;
  const int kbeg = 0, kend = p.K;

  extern __shared__ ushort_t smem[];      // 2 bufs x (16KB A + 16KB B) = 64KB
  ushort_t* sA = smem;
  ushort_t* sB = smem + 2 * 8192;

  const int tid = threadIdx.x;
  const int wid = tid >> 6, lane = tid & 63;
  const int wm = wid >> 2, wn = wid & 3;

  f32x4 acc[8][4];
#pragma unroll
  for (int i = 0; i < 8; i++)
#pragma unroll
    for (int j = 0; j < 4; j++) acc[i][j] = f32x4{0.f, 0.f, 0.f, 0.f};

  const int lr = lane >> 2;
  const int lcsw = (((lane & 3) ^ ((lr >> 1) & 3)) * 8);
  const int rT0 = wid * 16 + lr;
  const int rT1 = 128 + wid * 16 + lr;
  const ushort_t* gA0 = A + (size_t)(m0 + rT0) * p.K + lcsw;
  const ushort_t* gA1 = A + (size_t)(m0 + rT1) * p.K + lcsw;
  const ushort_t* gB0 = B + (size_t)(n0 + rT0) * p.K + lcsw;
  const ushort_t* gB1 = B + (size_t)(n0 + rT1) * p.K + lcsw;
  ushort_t* wA0 = &sA[wid * 512 + lane * 8];
  ushort_t* wA1 = &sA[(8 + wid) * 512 + lane * 8];
  ushort_t* wB0 = &sB[wid * 512 + lane * 8];
  ushort_t* wB1 = &sB[(8 + wid) * 512 + lane * 8];

  const int fr = lane & 15;
  const int q = lane >> 4;
  const int slot = (q ^ ((fr >> 1) & 3)) * 8;
  int offA[8], offB[4];
#pragma unroll
  for (int i = 0; i < 8; i++) offA[i] = (wm * 8 + i) * 512 + fr * 32 + slot;
#pragma unroll
  for (int j = 0; j < 4; j++) offB[j] = (wn * 4 + j) * 512 + fr * 32 + slot;

  const int nT = (kend - kbeg) >> 5;
  u32x4 rA0e, rA1e, rB0e, rB1e;
  u32x4 rA0o, rA1o, rB0o, rB1o;

  auto compute = [&](int co) {
    bf16x8 av[8], bv[4];
#pragma unroll
    for (int j = 0; j < 4; j++) bv[j] = *reinterpret_cast<const bf16x8*>(&sB[co + offB[j]]);
#pragma unroll
    for (int i = 0; i < 8; i++) av[i] = *reinterpret_cast<const bf16x8*>(&sA[co + offA[i]]);
    __builtin_amdgcn_s_setprio(1);
#pragma unroll
    for (int i = 0; i < 8; i++)
#pragma unroll
      for (int j = 0; j < 4; j++)
        acc[i][j] = __builtin_amdgcn_mfma_f32_16x16x32_bf16(av[i], bv[j], acc[i][j], 0, 0, 0);
    __builtin_amdgcn_s_setprio(0);
  };

  LOADT_BT(0, e);
  STORET_BT(0, e);
  if (nT > 1) LOADT_BT(1, o);
  PHASE_END();

  for (int t = 0; t < nT; t += 2) {
    compute(0);
    if (t + 1 < nT) STORET_BT(8192, o);
    if (t + 2 < nT) LOADT_BT(t + 2, e);
    PHASE_END();
    if (t + 1 < nT) {
      compute(8192);
      if (t + 2 < nT) STORET_BT(0, e);
      if (t + 3 < nT) LOADT_BT(t + 3, o);
      PHASE_END();
    }
  }

  const int fq = q;
  float* outf = p.outf;
  ushort_t* outb = p.outb;

#pragma unroll
  for (int i = 0; i < 8; i++) {
#pragma unroll
    for (int j = 0; j < 4; j++) {
#pragma unroll
      for (int r2 = 0; r2 < 4; r2++) {
        int row = m0 + wm * 128 + i * 16 + fq * 4 + r2;
        int col = n0 + wn * 64 + j * 16 + fr;
        size_t g = (size_t)row * p.N + col;
        float v = acc[i][j][r2];
        if (EPI == 0) {
          outf[g] = v + p.bias[col];
        } else if (EPI == 8) {
          outb[g] = f2bf(v + p.bias[col]);
        }
      }
    }
  }
}

// ---------- split-K combines ----------
__global__ __launch_bounds__(256) void k_comb(const float* part, const float* bias, float* out,
                                              int N, size_t MN, int S) {
  size_t e = ((size_t)blockIdx.x * 256 + threadIdx.x) * 4;
  if (e >= MN) return;
  float4 s = *(const float4*)(part + e);
  for (int p_ = 1; p_ < S; p_++) {
    float4 v = *(const float4*)(part + (size_t)p_ * MN + e);
    s.x += v.x; s.y += v.y; s.z += v.z; s.w += v.w;
  }
  if (bias) {
    int col = (int)(e % (size_t)N);
    s.x += bias[col]; s.y += bias[col + 1]; s.z += bias[col + 2]; s.w += bias[col + 3];
  }
  *(float4*)(out + e) = s;
}

// 128x128 compact-tri combine: S_bf16 = tril(sum_s part[s], -1)
__global__ __launch_bounds__(256) void k_combtri(const float* part, ushort_t* out, int Tt, int S,
                                                 int L) {
  int t = blockIdx.x, bz = blockIdx.y;
  int mt = (int)((sqrtf(8.f * t + 1.f) - 1.f) * 0.5f);
  while ((mt + 1) * (mt + 2) / 2 <= t) mt++;
  while (mt * (mt + 1) / 2 > t) mt--;
  int nt = t - mt * (mt + 1) / 2;
  const float* pb = part + ((size_t)bz * S * Tt + t) * 16384;
  ushort_t* ob = out + (size_t)bz * L * L;
  for (int e4 = threadIdx.x; e4 < 4096; e4 += 256) {
    int e = e4 * 4;
    float4 s = *(const float4*)(pb + e);
    for (int p_ = 1; p_ < S; p_++) {
      float4 v = *(const float4*)(pb + (size_t)p_ * Tt * 16384 + e);
      s.x += v.x; s.y += v.y; s.z += v.z; s.w += v.w;
    }
    int lr = e >> 7, lc2 = e & 127;
    int row = mt * 128 + lr, col = nt * 128 + lc2;
    ushort4 o;
    o.x = (col < row) ? f2bf(s.x) : (ushort_t)0;
    o.y = (col + 1 < row) ? f2bf(s.y) : (ushort_t)0;
    o.z = (col + 2 < row) ? f2bf(s.z) : (ushort_t)0;
    o.w = (col + 3 < row) ? f2bf(s.w) : (ushort_t)0;
    *(ushort4*)(&ob[(size_t)row * L + col]) = o;
  }
}

// ---------- auxiliary kernels ----------
__global__ __launch_bounds__(256) void k_conv(const float* in, ushort_t* out, size_t n) {
  size_t i = ((size_t)blockIdx.x * 256 + threadIdx.x) * 4;
  if (i >= n) return;
  float4 v = *(const float4*)(in + i);
  out[i] = f2bf(v.x); out[i + 1] = f2bf(v.y); out[i + 2] = f2bf(v.z); out[i + 3] = f2bf(v.w);
}

__global__ __launch_bounds__(256) void k_tconv(const float* in, ushort_t* out, int R, int C) {
  __shared__ float t[32][33];
  int c0 = blockIdx.x * 32, r0 = blockIdx.y * 32;
  int tx = threadIdx.x & 31, ty = threadIdx.x >> 5;
#pragma unroll
  for (int i = ty; i < 32; i += 8) t[i][tx] = in[(size_t)(r0 + i) * C + c0 + tx];
  __syncthreads();
#pragma unroll
  for (int i = ty; i < 32; i += 8) out[(size_t)(c0 + i) * R + r0 + tx] = f2bf(t[tx][i]);
}

// fused weight prep: one f32 read -> straight bf16 copy + transposed bf16 copy
__global__ __launch_bounds__(256) void k_wprep(const float* in, ushort_t* outS, ushort_t* outT,
                                               int R, int C) {
  __shared__ float t[32][33];
  int c0 = blockIdx.x * 32, r0 = blockIdx.y * 32;
  int tx = threadIdx.x & 31, ty = threadIdx.x >> 5;
#pragma unroll
  for (int i = ty; i < 32; i += 8) {
    float v = in[(size_t)(r0 + i) * C + c0 + tx];
    t[i][tx] = v;
    outS[(size_t)(r0 + i) * C + c0 + tx] = f2bf(v);
  }
  __syncthreads();
#pragma unroll
  for (int i = ty; i < 32; i += 8) outT[(size_t)(c0 + i) * R + r0 + tx] = f2bf(t[tx][i]);
}

__global__ __launch_bounds__(256) void k_tb2b(const ushort_t* in, ushort_t* out, int L, int C) {
  __shared__ ushort_t t[32][33];
  int b = blockIdx.z;
  const ushort_t* ib = in + (size_t)b * L * C;
  ushort_t* ob = out + (size_t)b * C * L;
  int c0 = blockIdx.x * 32, l0 = blockIdx.y * 32;
  int tx = threadIdx.x & 31, ty = threadIdx.x >> 5;
#pragma unroll
  for (int i = ty; i < 32; i += 8) t[i][tx] = ib[(size_t)(l0 + i) * C + c0 + tx];
  __syncthreads();
#pragma unroll
  for (int i = ty; i < 32; i += 8) ob[(size_t)(c0 + i) * L + l0 + tx] = t[tx][i];
}

__device__ __forceinline__ void blockRed2(float& a, float& b, float* red) {
#pragma unroll
  for (int o = 32; o; o >>= 1) { a += __shfl_down(a, o); b += __shfl_down(b, o); }
  int w = threadIdx.x >> 6;
  if ((threadIdx.x & 63) == 0) { red[w] = a; red[4 + w] = b; }
  __syncthreads();
  a = red[0] + red[1] + red[2] + red[3];
  b = red[4] + red[5] + red[6] + red[7];
  __syncthreads();
}

// fused split-K combine + LN forward (H3 path)
__global__ __launch_bounds__(256) void k_lncomb(const float* part, const float* bias,
                                                const float* sc, const float* bi, float* nout,
                                                float* rstd, ushort_t* yb, size_t MN, int D,
                                                int S) {
  __shared__ float red[8];
  int row = blockIdx.x;
  int d = threadIdx.x * 4;
  size_t g = (size_t)row * D + d;
  float4 v = *(const float4*)(part + g);
  for (int s_ = 1; s_ < S; s_++) {
    float4 w = *(const float4*)(part + (size_t)s_ * MN + g);
    v.x += w.x; v.y += w.y; v.z += w.z; v.w += w.w;
  }
  float4 bb = *(const float4*)(bias + d);
  v.x += bb.x; v.y += bb.y; v.z += bb.z; v.w += bb.w;
  float s1 = v.x + v.y + v.z + v.w;
  float s2 = v.x * v.x + v.y * v.y + v.z * v.z + v.w * v.w;
  blockRed2(s1, s2, red);
  float mu = s1 / D;
  float var = s2 / D - mu * mu;
  float rs = rsqrtf(var + 1e-6f);
  float4 nv;
  nv.x = (v.x - mu) * rs; nv.y = (v.y - mu) * rs; nv.z = (v.z - mu) * rs; nv.w = (v.w - mu) * rs;
  *(float4*)(nout + g) = nv;
  float4 scv = *(const float4*)(sc + d);
  float4 biv = *(const float4*)(bi + d);
  ushort4 o;
  o.x = f2bf(nv.x * scv.x + biv.x);
  o.y = f2bf(nv.y * scv.y + biv.y);
  o.z = f2bf(nv.z * scv.z + biv.z);
  o.w = f2bf(nv.w * scv.w + biv.w);
  *(ushort4*)(yb + g) = o;
  if (threadIdx.x == 0) rstd[row] = rs;
}

__global__ __launch_bounds__(256) void k_lnfwd2(const float* X, const float* fs, const float* fb,
                                                ushort_t* yb, int D) {
  __shared__ float red[8];
  int row = blockIdx.x;
  const float* x = X + (size_t)row * D;
  float s = 0.f, s2 = 0.f;
  for (int d = threadIdx.x; d < D; d += 256) { float v = x[d]; s += v; s2 += v * v; }
  blockRed2(s, s2, red);
  float mu = s / D;
  float var = s2 / D - mu * mu;
  float rs = rsqrtf(var + 1e-6f);
  for (int d = threadIdx.x; d < D; d += 256) {
    size_t g = (size_t)row * D + d;
    float nv = (x[d] - mu) * rs;
    yb[g] = f2bf(nv * fs[g] + fb[g]);
  }
}

__global__ __launch_bounds__(256) void k_lnbwd(const float* G, const float* nn, const float* rstd,
                                               const float* sc, ushort_t* g3b, float* gsc, int D) {
  __shared__ float red[8];
  int row = blockIdx.x;
  const float* g = G + (size_t)row * D;
  const float* n_ = nn + (size_t)row * D;
  float sa = 0.f, sb = 0.f;
  for (int d = threadIdx.x; d < D; d += 256) {
    float dn = g[d] * sc[d];
    sa += dn; sb += dn * n_[d];
  }
  blockRed2(sa, sb, red);
  float a = sa / D, b = sb / D, rs = rstd[row];
  for (int d = threadIdx.x; d < D; d += 256) {
    size_t gi = (size_t)row * D + d;
    float dn = g[d] * sc[d];
    g3b[gi] = f2bf(rs * (dn - a - n_[d] * b));
    gsc[gi] = g[d] * n_[d];
  }
}

__global__ __launch_bounds__(256) void k_wsum(const float* w, float* o, int n) {
  __shared__ float red[4];
  float s = 0.f;
  for (int i = threadIdx.x; i < n; i += 256) s += w[i];
#pragma unroll
  for (int d = 32; d; d >>= 1) s += __shfl_down(s, d);
  if ((threadIdx.x & 63) == 0) red[threadIdx.x >> 6] = s;
  __syncthreads();
  if (threadIdx.x == 0) o[0] = fmaxf(red[0] + red[1] + red[2] + red[3], 1e-8f);
}

// register-staged fused softmax-grad: V=8192, 256 thr, 32 elem/thread in VGPRs.
__global__ __launch_bounds__(256) void k_softgrad(const ushort_t* logits, const float* labels,
                                                  const float* w, const float* wsum,
                                                  ushort_t* dlb, int V) {
  __shared__ float red[8];
  const int row = blockIdx.x;
  const int tid = threadIdx.x;
  const ushort_t* l = logits + (size_t)row * V + tid * 32;
  const float* y = labels + (size_t)row * V + tid * 32;
  float lv[32], yv[32];
#pragma unroll
  for (int i = 0; i < 4; i++) {
    us8 u = *reinterpret_cast<const us8*>(l + i * 8);
#pragma unroll
    for (int j = 0; j < 8; j++) lv[i * 8 + j] = bf2f(u[j]);
  }
#pragma unroll
  for (int i = 0; i < 8; i++) {
    float4 v = *reinterpret_cast<const float4*>(y + i * 4);
    yv[i * 4] = v.x; yv[i * 4 + 1] = v.y; yv[i * 4 + 2] = v.z; yv[i * 4 + 3] = v.w;
  }
  float m = lv[0], t = yv[0];
#pragma unroll
  for (int i = 1; i < 32; i++) { m = fmaxf(m, lv[i]); t += yv[i]; }
#pragma unroll
  for (int o = 32; o; o >>= 1) { m = fmaxf(m, __shfl_down(m, o)); t += __shfl_down(t, o); }
  int wv = tid >> 6;
  if ((tid & 63) == 0) { red[wv] = m; red[4 + wv] = t; }
  __syncthreads();
  m = fmaxf(fmaxf(red[0], red[1]), fmaxf(red[2], red[3]));
  t = red[4] + red[5] + red[6] + red[7];
  __syncthreads();
  float s = 0.f;
#pragma unroll
  for (int i = 0; i < 32; i++) { lv[i] = expf(lv[i] - m); s += lv[i]; }
#pragma unroll
  for (int o = 32; o; o >>= 1) s += __shfl_down(s, o);
  if ((tid & 63) == 0) red[wv] = s;
  __syncthreads();
  s = red[0] + red[1] + red[2] + red[3];
  float c = w[row] / wsum[0];
  float ci = c * t / s;
  ushort_t* dl = dlb + (size_t)row * V + tid * 32;
#pragma unroll
  for (int i = 0; i < 4; i++) {
    us8 o;
#pragma unroll
    for (int j = 0; j < 8; j++) o[j] = f2bf(ci * lv[i * 8 + j] - c * yv[i * 8 + j]);
    *reinterpret_cast<us8*>(dl + i * 8) = o;
  }
}

__global__ __launch_bounds__(256) void k_scanpart(const float* gs, const float* gb, float* ps,
                                                  float* pb, int L, int D) {
  int d = blockIdx.x * 256 + threadIdx.x;
  int seg = blockIdx.y, b = blockIdx.z;
  const int SEGL = L / 16;
  size_t base = ((size_t)b * L + seg * SEGL) * D + d;
  float s1 = 0.f, s2 = 0.f;
  for (int i = 0; i < SEGL; i++) { s1 += gs[base + (size_t)i * D]; s2 += gb[base + (size_t)i * D]; }
  size_t pi = ((size_t)b * 16 + seg) * D + d;
  ps[pi] = s1; pb[pi] = s2;
}

__global__ __launch_bounds__(256) void k_scanapply(const float* gs, const float* gb,
                                                   const float* ps, const float* pb,
                                                   const float* sc, const float* bi,
                                                   const float* steps, float* fs, float* fb,
                                                   int L, int D) {
  int d = blockIdx.x * 256 + threadIdx.x;
  int seg = blockIdx.y, b = blockIdx.z;
  const int SEGL = L / 16;
  float ss = steps[3];
  float rs_ = 0.f, rb_ = 0.f;
  for (int s = 0; s < seg; s++) {
    size_t pi = ((size_t)b * 16 + s) * D + d;
    rs_ += ps[pi]; rb_ += pb[pi];
  }
  float s0 = sc[d], b0 = bi[d];
  size_t base = ((size_t)b * L + seg * SEGL) * D + d;
  for (int i = 0; i < SEGL; i++) {
    size_t g = base + (size_t)i * D;
    fs[g] = s0 - ss * rs_;
    fb[g] = b0 - ss * rb_;
    rs_ += gs[g]; rb_ += gb[g];
  }
}

// ---------- orchestration ----------
extern "C" void kernel_launch(void* const* d_in, const int* in_sizes, int n_in, void* d_out,
                              int out_size, void* d_ws, size_t ws_size, hipStream_t stream) {
  const float* x        = (const float*)d_in[0];
  const float* labels   = (const float*)d_in[1];
  const float* weights  = (const float*)d_in[2];
  const float* W1       = (const float*)d_in[3];
  const float* b1       = (const float*)d_in[4];
  const float* W2       = (const float*)d_in[5];
  const float* b2       = (const float*)d_in[6];
  const float* ln_scale = (const float*)d_in[7];
  const float* ln_bias  = (const float*)d_in[8];
  const float* Wu       = (const float*)d_in[9];
  const float* bu       = (const float*)d_in[10];
  const float* steps    = (const float*)d_in[11];

  const int BL = in_sizes[2];   // 4096
  const int D  = in_sizes[7];   // 1024
  const int F  = in_sizes[4];   // 4096
  const int V  = in_sizes[10];  // 8192
  const int Bb = 2, L = BL / Bb;
  const int T1t = (L / 128) * (L / 128 + 1) / 2;   // 136 live 128-tri tiles
  const unsigned SMEM = 2 * 16384 * 2;             // 64 KB dynamic LDS (gemm256)

  char* ws = (char*)d_ws;
  size_t off = 0;
  auto take = [&](size_t b) { char* p = ws + off; off = (off + b + 255) & ~(size_t)255; return p; };

  ushort_t* xb   = (ushort_t*)take((size_t)BL * D * 2);
  ushort_t* w1t  = (ushort_t*)take((size_t)F * D * 2);
  ushort_t* w2t  = (ushort_t*)take((size_t)D * F * 2);
  ushort_t* w2b  = (ushort_t*)take((size_t)F * D * 2);
  ushort_t* wut  = (ushort_t*)take((size_t)V * D * 2);
  ushort_t* wub  = (ushort_t*)take((size_t)D * V * 2);
  ushort_t* H1b  = (ushort_t*)take((size_t)BL * F * 2);
  ushort_t* H2b  = (ushort_t*)take((size_t)BL * F * 2);
  float*    nbuf = (float*)take((size_t)BL * D * 4);
  float*    rstd = (float*)take((size_t)BL * 4);
  ushort_t* h4b  = (ushort_t*)take((size_t)BL * D * 2);
  float*    wsumb= (float*)take(256);
  float*    G4   = (float*)take((size_t)BL * D * 4);   // also g_bias
  float*    gsc  = (float*)take((size_t)BL * D * 4);   // g_scale
  ushort_t* g3b  = (ushort_t*)take((size_t)BL * D * 2);
  ushort_t* g3t  = (ushort_t*)take((size_t)BL * D * 2);
  float*    fs   = (float*)take((size_t)BL * D * 4);
  float*    fb   = (float*)take((size_t)BL * D * 4);
  ushort_t* x4b  = (ushort_t*)take((size_t)BL * D * 2);
  float*    psc  = (float*)take((size_t)Bb * 16 * D * 4);
  float*    pbi  = (float*)take((size_t)Bb * 16 * D * 4);
  // poolA (134MB): logitsb bf16 / split-K partials -> later {g1b, g1t, S1b, x2b}
  char* poolA = take((size_t)BL * V * 4);
  ushort_t* logitsb = (ushort_t*)poolA;
  float*    partA  = (float*)poolA;
  ushort_t* g1b = (ushort_t*)poolA;
  ushort_t* g1t = (ushort_t*)(poolA + (size_t)BL * F * 2);
  ushort_t* S1b = (ushort_t*)(poolA + (size_t)BL * F * 4);
  ushort_t* x2b = (ushort_t*)(poolA + (size_t)BL * F * 4 + (size_t)Bb * L * L * 2);
  // poolB (64MB): dlb bf16 -> later {S2b, X3, x3}; head hosts S1 partials (36MB)
  char* poolB = take((size_t)BL * V * 2);
  ushort_t* dlb = (ushort_t*)poolB;
  float*    partS1 = (float*)poolB;
  ushort_t* S2b = (ushort_t*)poolB;
  float*    X3  = (float*)(poolB + (size_t)Bb * L * L * 2);
  float*    x3  = (float*)(poolB + (size_t)Bb * L * L * 2 + (size_t)BL * D * 4);

  dim3 blk(256), blk5(512);
  const size_t MN_D = (size_t)BL * D;

  k_conv<<<dim3((unsigned)((size_t)BL * D / 1024)), blk, 0, stream>>>(x, xb, (size_t)BL * D);
  k_tconv<<<dim3(F / 32, D / 32), blk, 0, stream>>>(W1, w1t, D, F);
  k_wprep<<<dim3(D / 32, F / 32), blk, 0, stream>>>(W2, w2b, w2t, F, D);   // straight + (D,F)T
  k_wprep<<<dim3(V / 32, D / 32), blk, 0, stream>>>(Wu, wub, wut, D, V);   // straight + (V,D)T

  GemmP p;
  auto clr = [&]() { p = GemmP{}; };

  // 1) H1b = bf16(x@W1+b1) ; H2b = bf16(relu^2)   [128^2]
  clr(); p.A = xb; p.B = w1t; p.M = BL; p.N = F; p.K = D;
  p.outb = H1b; p.outb2 = H2b; p.bias = b1;
  gemm_bt<1><<<dim3(F / 128, BL / 128, 1), blk, 0, stream>>>(p);
  // 2) H3 partials [split-K 4] -> fused combine+LN fwd
  clr(); p.A = H2b; p.B = w2t; p.M = BL; p.N = D; p.K = F;
  p.part = partA; p.ksplit = 4; p.Kc = F / 4;
  gemm_bt<6><<<dim3(D / 128, BL / 128, 4), blk, 0, stream>>>(p);
  k_lncomb<<<dim3(BL), blk, 0, stream>>>(partA, b2, ln_scale, ln_bias, nbuf, rstd, h4b, MN_D, D, 4);
  // 4) logits = bf16(h4@Wu + bu)   [256^2]
  clr(); p.A = h4b; p.B = wut; p.M = BL; p.N = V; p.K = D; p.outb = logitsb; p.bias = bu;
  gemm256<8><<<dim3(V / 256, BL / 256, 1), blk5, SMEM, stream>>>(p);
  // 5) fused softmax grad (register-staged)
  k_wsum<<<dim3(1), blk, 0, stream>>>(weights, wsumb, BL);
  k_softgrad<<<dim3(BL), blk, 0, stream>>>(logitsb, labels, weights, wsumb, dlb, V);
  // 6) G4 = dlogits @ Wu^T   [split-K 4]
  clr(); p.A = dlb; p.B = wub; p.M = BL; p.N = D; p.K = V;
  p.part = partA; p.ksplit = 4; p.Kc = V / 4;
  gemm_bt<6><<<dim3(D / 128, BL / 128, 4), blk, 0, stream>>>(p);
  k_comb<<<dim3((unsigned)(MN_D / 1024)), blk, 0, stream>>>(partA, nullptr, G4, D, MN_D, 4);
  // 7) LN bwd -> g3, g_scale
  k_lnbwd<<<dim3(BL), blk, 0, stream>>>(G4, nbuf, rstd, ln_scale, g3b, gsc, D);
  // 8) g1 = (g3 @ W2^T) * 2*sqrt(H2)
  clr(); p.A = g3b; p.B = w2b; p.M = BL; p.N = F; p.K = D; p.outb = g1b; p.auxb = H2b;
  gemm_bt<2><<<dim3(F / 128, BL / 128, 1), blk, 0, stream>>>(p);
  // 9) transposes for attention V-operands
  k_tb2b<<<dim3(F / 32, L / 32, Bb), blk, 0, stream>>>(g1b, g1t, L, F);
  k_tb2b<<<dim3(D / 32, L / 32, Bb), blk, 0, stream>>>(g3b, g3t, L, D);
  // 10) S1 = tril(x x^T, -1)   [split-K 2, compact-tri 136 tiles, partials poolB]
  clr(); p.A = xb; p.B = xb; p.M = L; p.N = L; p.K = D;
  p.sA = (long long)L * D; p.sB = (long long)L * D;
  p.part = partS1; p.ksplit = 2; p.Kc = D / 2; p.Tt = T1t;
  gemm_bt<7><<<dim3(T1t, 1, Bb * 2), blk, 0, stream>>>(p);
  k_combtri<<<dim3(T1t, Bb), blk, 0, stream>>>(partS1, S1b, T1t, 2, L);
  // 11) x2 = relu(H1 - ss0 * S1@g1)^2   [K-limited, aux = bf16 H1b]
  clr(); p.A = S1b; p.B = g1t; p.M = L; p.N = F; p.K = L;
  p.sA = (long long)L * L; p.sB = (long long)F * L;
  p.outb = x2b; p.sOutB = (long long)L * F; p.auxb = H1b; p.sAuxF = (long long)L * F;
  p.steps = steps;
  gemm_bt<4><<<dim3(F / 128, L / 128, Bb), blk, 0, stream>>>(p);
  // 12) X3 = x2@W2 + b2   [split-K 4]
  clr(); p.A = x2b; p.B = w2t; p.M = BL; p.N = D; p.K = F;
  p.part = partA; p.ksplit = 4; p.Kc = F / 4;
  gemm_bt<6><<<dim3(D / 128, BL / 128, 4), blk, 0, stream>>>(p);
  k_comb<<<dim3((unsigned)(MN_D / 1024)), blk, 0, stream>>>(partA, b2, X3, D, MN_D, 4);
  // 13) S2 = tril(x2 H2^T, -1)   [split-K 2, compact-tri, partials poolA head]
  clr(); p.A = x2b; p.B = H2b; p.M = L; p.N = L; p.K = F;
  p.sA = (long long)L * F; p.sB = (long long)L * F;
  p.part = partA; p.ksplit = 2; p.Kc = F / 2; p.Tt = T1t;
  gemm_bt<7><<<dim3(T1t, 1, Bb * 2), blk, 0, stream>>>(p);
  k_combtri<<<dim3(T1t, Bb), blk, 0, stream>>>(partA, S2b, T1t, 2, L);
  // 14) x3 = X3 - ss2 * S2@g3   [K-limited]
  clr(); p.A = S2b; p.B = g3t; p.M = L; p.N = D; p.K = L;
  p.sA = (long long)L * L; p.sB = (long long)D * L;
  p.outf = x3; p.sOutF = (long long)L * D; p.auxf = X3; p.sAuxF = (long long)L * D; p.steps = steps;
  gemm_bt<5><<<dim3(D / 128, L / 128, Bb), blk, 0, stream>>>(p);
  // 15) exclusive cumsums -> fast_scale / fast_bias
  k_scanpart<<<dim3(D / 256, 16, Bb), blk, 0, stream>>>(gsc, G4, psc, pbi, L, D);
  k_scanapply<<<dim3(D / 256, 16, Bb), blk, 0, stream>>>(gsc, G4, psc, pbi, ln_scale, ln_bias,
                                                         steps, fs, fb, L, D);
  // 16) x4 = LN(x3)*fast_scale + fast_bias
  k_lnfwd2<<<dim3(BL), blk, 0, stream>>>(x3, fs, fb, x4b, D);
  // 17) out = x4@Wu + bu   [256^2]
  clr(); p.A = x4b; p.B = wut; p.M = BL; p.N = V; p.K = D; p.outf = (float*)d_out; p.bias = bu;
  gemm256<0><<<dim3(V / 256, BL / 256, 1), blk5, SMEM, stream>>>(p);
}

// Round 13
// 1073.941 us; speedup vs baseline: 1.0319x; 1.0319x over previous
//
#include <hip/hip_runtime.h>
#include <cstdint>

typedef unsigned short ushort_t;
typedef __bf16 bf16x8 __attribute__((ext_vector_type(8)));
typedef float f32x4 __attribute__((ext_vector_type(4)));
typedef ushort_t us8 __attribute__((ext_vector_type(8)));

// ---------- helpers ----------
__device__ __forceinline__ ushort_t f2bf(float f) {
  union { float f; unsigned int u; } v; v.f = f;
  unsigned int u = v.u;
  unsigned int r = (u + 0x7fffu + ((u >> 16) & 1u)) >> 16;
  return (ushort_t)r;
}
__device__ __forceinline__ float bf2f(ushort_t u) {
  union { unsigned int u; float f; } v; v.u = ((unsigned int)u) << 16; return v.f;
}

#define GLOAD16(gp, lp)                                                              \
  __builtin_amdgcn_global_load_lds(                                                  \
      reinterpret_cast<const __attribute__((address_space(1))) unsigned int*>(       \
          reinterpret_cast<uintptr_t>(gp)),                                          \
      reinterpret_cast<__attribute__((address_space(3))) unsigned int*>(             \
          reinterpret_cast<uintptr_t>(lp)),                                          \
      16, 0, 0)

// EPI: 0 = outf = acc + bias                     (out)
//      8 = outb = bf16(acc + bias)               (logits)
//      1 = outb = bf16(acc+bias); outb2 = bf16(relu^2)    (H1b + H2b)
//      2 = outb = bf16(acc * 2*sqrt(auxb))       (g1)
//      4 = outb = bf16(relu(bf2f(auxb) - ss0*acc)^2); K-limit  (x2)
//      5 = outf = auxf - ss2*acc; K-limit        (x3, 128^2 kernel)
//      6 = split-K partial, full-matrix f32      (H3, G4, X3 stage 1)
//      7 = split-K partial, compact-tri grid, 256x256 tiles   (S1, S2 stage 1)
struct GemmP {
  const ushort_t* A; const ushort_t* B;
  int M, N, K;
  long long sA, sB;
  float* outf;   long long sOutF;
  ushort_t* outb; long long sOutB;
  ushort_t* outb2;
  const float* bias;
  const float* auxf; long long sAuxF;   // sAuxF doubles as aux (f32 or bf16) stride
  const ushort_t* auxb;
  const float* steps;
  float* part; int ksplit, Kc, Tt;
};

// XCD slab swizzle (R13): when gridDim.x%8==0, each XCD owns an nt-slab of
// gx/8 columns x ALL mt rows -> per-XCD B working set = slab*512KB <= ~1MB,
// L2-RESIDENT; B re-reads across the mt sweep become L2 hits. Bijective.
// Fallback: m204 bijective swizzle (proven).
__device__ __forceinline__ void tile_map(int& mt, int& nt) {
  const int orig = blockIdx.y * gridDim.x + blockIdx.x;
  const int gx = gridDim.x;
  if ((gx & 7) == 0) {
    const int slab = gx >> 3;
    const int xcd = orig & 7, loc = orig >> 3;
    nt = xcd * slab + loc % slab;
    mt = loc / slab;
  } else {
    const int nwg = gx * gridDim.y;
    const int xcd = orig & 7, loc = orig >> 3;
    const int q8 = nwg >> 3, r8 = nwg & 7;
    const int wg = (xcd < r8) ? (xcd * (q8 + 1) + loc) : (r8 * (q8 + 1) + (xcd - r8) * q8 + loc);
    nt = wg % gx; mt = wg / gx;
  }
}
__device__ __forceinline__ int tri_wg() {   // m204 bijective over tri grid
  const int orig = blockIdx.y * gridDim.x + blockIdx.x;
  const int nwg = gridDim.x * gridDim.y;
  const int xcd = orig & 7, loc = orig >> 3;
  const int q8 = nwg >> 3, r8 = nwg & 7;
  return (xcd < r8) ? (xcd * (q8 + 1) + loc) : (r8 * (q8 + 1) + (xcd - r8) * q8 + loc);
}

// ---------- 256x256 GEMM (R9-proven): 8 waves, BK=32, 4-buf depth-3 ----------
template <int EPI>
__global__ __launch_bounds__(512, 2) void gemm256(GemmP p) {
  int mt, nt;
  int wg = 0;
  if (EPI == 7) {            // compact lower-tri tile index -> (mt, nt)
    wg = tri_wg();
    int t_ = wg;
    mt = (int)((sqrtf(8.f * t_ + 1.f) - 1.f) * 0.5f);
    while ((mt + 1) * (mt + 2) / 2 <= t_) mt++;
    while (mt * (mt + 1) / 2 > t_) mt--;
    nt = t_ - mt * (mt + 1) / 2;
  } else {
    tile_map(mt, nt);
  }
  const int m0 = mt * 256, n0 = nt * 256;

  int bz = blockIdx.z, ks = 0;
  if (EPI == 6 || EPI == 7) { bz = blockIdx.z / p.ksplit; ks = blockIdx.z % p.ksplit; }

  const ushort_t* A = p.A + (size_t)bz * p.sA;
  const ushort_t* B = p.B + (size_t)bz * p.sB;

  int kbeg = 0, kend = p.K;
  if (EPI == 6 || EPI == 7) { kbeg = ks * p.Kc; kend = kbeg + p.Kc; }
  else if (EPI == 4) kend = min(p.K, m0 + 256);

  extern __shared__ ushort_t smem[];      // 4 bufs x (16KB A + 16KB B) = 128KB
  ushort_t* sA = smem;
  ushort_t* sB = smem + 4 * 8192;

  const int tid = threadIdx.x;
  const int wid = tid >> 6, lane = tid & 63;
  const int wm = wid >> 2, wn = wid & 3;

  f32x4 acc[8][4];
#pragma unroll
  for (int i = 0; i < 8; i++)
#pragma unroll
    for (int j = 0; j < 4; j++) acc[i][j] = f32x4{0.f, 0.f, 0.f, 0.f};

  // staging: chunk = 16 rows x 32 cols = 1KB (64 lanes x 16B). Source col
  // pre-swizzled (T2) so the linear gload_lds dest lands swizzled.
  const int lr = lane >> 2;
  const int lcsw = (((lane & 3) ^ ((lr >> 1) & 3)) * 8);
  const int rT0 = wid * 16 + lr;
  const int rT1 = 128 + wid * 16 + lr;
  const ushort_t* gA0 = A + (size_t)(m0 + rT0) * p.K + lcsw;
  const ushort_t* gA1 = A + (size_t)(m0 + rT1) * p.K + lcsw;
  const ushort_t* gB0 = B + (size_t)(n0 + rT0) * p.K + lcsw;
  const ushort_t* gB1 = B + (size_t)(n0 + rT1) * p.K + lcsw;
  ushort_t* lA0 = &sA[wid * 512];
  ushort_t* lA1 = &sA[(8 + wid) * 512];
  ushort_t* lB0 = &sB[wid * 512];
  ushort_t* lB1 = &sB[(8 + wid) * 512];

  // swizzled ds_read offsets (loop-invariant)
  const int fr = lane & 15;
  const int q = lane >> 4;
  const int slot = (q ^ ((fr >> 1) & 3)) * 8;
  int offA[8], offB[4];
#pragma unroll
  for (int i = 0; i < 8; i++) offA[i] = (wm * 8 + i) * 512 + fr * 32 + slot;
#pragma unroll
  for (int j = 0; j < 4; j++) offB[j] = (wn * 4 + j) * 512 + fr * 32 + slot;

  const int nT = (kend - kbeg) >> 5;    // BK = 32
  auto stage4 = [&](int t) {            // tile t -> buf t%4 (4 gloads)
    const int kk = kbeg + t * 32;
    const int o = (t & 3) * 8192;
    GLOAD16(gA0 + kk, lA0 + o);
    GLOAD16(gA1 + kk, lA1 + o);
    GLOAD16(gB0 + kk, lB0 + o);
    GLOAD16(gB1 + kk, lB1 + o);
  };
  stage4(0);
  if (nT > 1) stage4(1);
  if (nT > 2) stage4(2);
  if (nT > 2)      { asm volatile("s_waitcnt vmcnt(8)" ::: "memory"); }
  else if (nT > 1) { asm volatile("s_waitcnt vmcnt(4)" ::: "memory"); }
  else             { asm volatile("s_waitcnt vmcnt(0)" ::: "memory"); }
  __builtin_amdgcn_s_barrier();

  for (int t = 0; t < nT; ++t) {
    const int co = (t & 3) * 8192;
    if (t + 3 < nT) stage4(t + 3);           // keep the queue deep
    __builtin_amdgcn_sched_barrier(0);       // pin stage issue ahead of reads
    bf16x8 av[8], bv[4];
#pragma unroll
    for (int j = 0; j < 4; j++) bv[j] = *reinterpret_cast<const bf16x8*>(&sB[co + offB[j]]);
#pragma unroll
    for (int i = 0; i < 8; i++) av[i] = *reinterpret_cast<const bf16x8*>(&sA[co + offA[i]]);
    __builtin_amdgcn_s_setprio(1);
#pragma unroll
    for (int i = 0; i < 8; i++)
#pragma unroll
      for (int j = 0; j < 4; j++)
        acc[i][j] = __builtin_amdgcn_mfma_f32_16x16x32_bf16(av[i], bv[j], acc[i][j], 0, 0, 0);
    __builtin_amdgcn_s_setprio(0);
    if (t + 3 < nT)      { asm volatile("s_waitcnt vmcnt(8)" ::: "memory"); }
    else if (t + 2 < nT) { asm volatile("s_waitcnt vmcnt(4)" ::: "memory"); }
    else if (t + 1 < nT) { asm volatile("s_waitcnt vmcnt(0)" ::: "memory"); }
    __builtin_amdgcn_s_barrier();
  }

  const int fq = q;
  float ss = 0.f;
  if (EPI == 4) ss = p.steps[0];
  float* outf = p.outf ? p.outf + (size_t)bz * p.sOutF : nullptr;
  ushort_t* outb = p.outb ? p.outb + (size_t)bz * p.sOutB : nullptr;
  ushort_t* outb2 = p.outb2;
  const ushort_t* auxb = p.auxb ? p.auxb + (size_t)bz * p.sAuxF : nullptr;
  float* partT = nullptr;
  if (EPI == 6) partT = p.part + (size_t)blockIdx.z * p.M * p.N;
  if (EPI == 7) partT = p.part + ((size_t)blockIdx.z * p.Tt + wg) * 65536;

#pragma unroll
  for (int i = 0; i < 8; i++) {
#pragma unroll
    for (int j = 0; j < 4; j++) {
#pragma unroll
      for (int r2 = 0; r2 < 4; r2++) {
        int lrow = wm * 128 + i * 16 + fq * 4 + r2;
        int lcol = wn * 64 + j * 16 + fr;
        int row = m0 + lrow, col = n0 + lcol;
        size_t g = (size_t)row * p.N + col;
        float v = acc[i][j][r2];
        if (EPI == 0) {
          outf[g] = v + (p.bias ? p.bias[col] : 0.f);
        } else if (EPI == 8) {
          outb[g] = f2bf(v + p.bias[col]);
        } else if (EPI == 1) {
          v += p.bias[col];
          outb[g] = f2bf(v);
          float rl = fmaxf(v, 0.f);
          outb2[g] = f2bf(rl * rl);
        } else if (EPI == 2) {
          outb[g] = f2bf(v * 2.f * sqrtf(bf2f(auxb[g])));
        } else if (EPI == 4) {
          float x1 = bf2f(auxb[g]) - ss * v;
          float rl = fmaxf(x1, 0.f);
          outb[g] = f2bf(rl * rl);
        } else if (EPI == 6) {
          partT[g] = v;
        } else if (EPI == 7) {
          partT[lrow * 256 + lcol] = v;
        }
      }
    }
  }
}

// ---------- 128x128 GEMM (R9-proven) -- kept for x3 (EPI 5) ----------
template <int EPI>
__global__ __launch_bounds__(256) void gemm_bt(GemmP p) {
  int mt, nt;
  tile_map(mt, nt);
  const int m0 = mt * 128, n0 = nt * 128;
  const int bz = blockIdx.z;

  const ushort_t* A = p.A + (size_t)bz * p.sA;
  const ushort_t* B = p.B + (size_t)bz * p.sB;

  int kend = p.K;
  if (EPI == 5) kend = min(p.K, m0 + 128);

  __shared__ ushort_t sA[4 * 128 * 32];
  __shared__ ushort_t sB[4 * 128 * 32];

  const int tid = threadIdx.x;
  const int wid = tid >> 6, lane = tid & 63;
  const int wm = wid >> 1, wn = wid & 1;

  f32x4 acc[4][4];
#pragma unroll
  for (int i = 0; i < 4; i++)
#pragma unroll
    for (int j = 0; j < 4; j++) acc[i][j] = f32x4{0.f, 0.f, 0.f, 0.f};

  const int lr = lane >> 2;
  const int lc = (lane & 3) * 8;
  const int rA0 = wid * 16 + lr;
  const int rA1 = 64 + wid * 16 + lr;
  const ushort_t* gA0 = A + (size_t)(m0 + rA0) * p.K + lc;
  const ushort_t* gA1 = A + (size_t)(m0 + rA1) * p.K + lc;
  const ushort_t* gB0 = B + (size_t)(n0 + rA0) * p.K + lc;
  const ushort_t* gB1 = B + (size_t)(n0 + rA1) * p.K + lc;
  ushort_t* lA0 = &sA[wid * 512];
  ushort_t* lA1 = &sA[(4 + wid) * 512];
  ushort_t* lB0 = &sB[wid * 512];
  ushort_t* lB1 = &sB[(4 + wid) * 512];

  const int fr = lane & 15;
  const int kb = (lane >> 4) * 8;

  const int nIter = kend >> 5;
  auto stage = [&](int t) {
    const int kk = t * 32;
    const int o = (t & 3) * 4096;
    GLOAD16(gA0 + kk, lA0 + o);
    GLOAD16(gA1 + kk, lA1 + o);
    GLOAD16(gB0 + kk, lB0 + o);
    GLOAD16(gB1 + kk, lB1 + o);
  };
  stage(0);
  if (nIter > 1) stage(1);
  if (nIter > 2) stage(2);
  if (nIter > 2)      { asm volatile("s_waitcnt vmcnt(8)" ::: "memory"); }
  else if (nIter > 1) { asm volatile("s_waitcnt vmcnt(4)" ::: "memory"); }
  else                { asm volatile("s_waitcnt vmcnt(0)" ::: "memory"); }
  __builtin_amdgcn_s_barrier();

  for (int t = 0; t < nIter; ++t) {
    const int co = (t & 3) * 4096;
    if (t + 3 < nIter) stage(t + 3);
    __builtin_amdgcn_sched_barrier(0);
    bf16x8 av[4], bv[4];
#pragma unroll
    for (int i = 0; i < 4; i++) {
      av[i] = *reinterpret_cast<const bf16x8*>(&sA[co + (wm * 64 + i * 16 + fr) * 32 + kb]);
      bv[i] = *reinterpret_cast<const bf16x8*>(&sB[co + (wn * 64 + i * 16 + fr) * 32 + kb]);
    }
    __builtin_amdgcn_s_setprio(1);
#pragma unroll
    for (int i = 0; i < 4; i++)
#pragma unroll
      for (int j = 0; j < 4; j++)
        acc[i][j] = __builtin_amdgcn_mfma_f32_16x16x32_bf16(av[i], bv[j], acc[i][j], 0, 0, 0);
    __builtin_amdgcn_s_setprio(0);
    if (t + 3 < nIter)      { asm volatile("s_waitcnt vmcnt(8)" ::: "memory"); }
    else if (t + 2 < nIter) { asm volatile("s_waitcnt vmcnt(4)" ::: "memory"); }
    else if (t + 1 < nIter) { asm volatile("s_waitcnt vmcnt(0)" ::: "memory"); }
    __builtin_amdgcn_s_barrier();
  }

  const int fq = lane >> 4;
  float ss = (EPI == 5) ? p.steps[2] : 0.f;
  float* outf = p.outf ? p.outf + (size_t)bz * p.sOutF : nullptr;
  const float* auxf = p.auxf ? p.auxf + (size_t)bz * p.sAuxF : nullptr;

#pragma unroll
  for (int i = 0; i < 4; i++) {
#pragma unroll
    for (int j = 0; j < 4; j++) {
#pragma unroll
      for (int r2 = 0; r2 < 4; r2++) {
        int row = m0 + wm * 64 + i * 16 + fq * 4 + r2;
        int col = n0 + wn * 64 + j * 16 + fr;
        size_t g = (size_t)row * p.N + col;
        float v = acc[i][j][r2];
        if (EPI == 5) {
          outf[g] = auxf[g] - ss * v;
        } else {
          outf[g] = v + (p.bias ? p.bias[col] : 0.f);
        }
      }
    }
  }
}

// ---------- split-K combines ----------
__global__ __launch_bounds__(256) void k_comb(const float* part, const float* bias, float* out,
                                              int N, size_t MN, int S) {
  size_t e = ((size_t)blockIdx.x * 256 + threadIdx.x) * 4;
  if (e >= MN) return;
  float4 s = *(const float4*)(part + e);
  for (int p_ = 1; p_ < S; p_++) {
    float4 v = *(const float4*)(part + (size_t)p_ * MN + e);
    s.x += v.x; s.y += v.y; s.z += v.z; s.w += v.w;
  }
  if (bias) {
    int col = (int)(e % (size_t)N);
    s.x += bias[col]; s.y += bias[col + 1]; s.z += bias[col + 2]; s.w += bias[col + 3];
  }
  *(float4*)(out + e) = s;
}

// 256x256 compact-tri combine: S_bf16 = tril(sum_s part[s], -1)
__global__ __launch_bounds__(256) void k_combtri(const float* part, ushort_t* out, int Tt, int S,
                                                 int L) {
  int t = blockIdx.x, bz = blockIdx.y;
  int mt = (int)((sqrtf(8.f * t + 1.f) - 1.f) * 0.5f);
  while ((mt + 1) * (mt + 2) / 2 <= t) mt++;
  while (mt * (mt + 1) / 2 > t) mt--;
  int nt = t - mt * (mt + 1) / 2;
  const float* pb = part + ((size_t)bz * S * Tt + t) * 65536;
  ushort_t* ob = out + (size_t)bz * L * L;
  for (int e4 = threadIdx.x; e4 < 16384; e4 += 256) {
    int e = e4 * 4;
    float4 s = *(const float4*)(pb + e);
    for (int p_ = 1; p_ < S; p_++) {
      float4 v = *(const float4*)(pb + (size_t)p_ * Tt * 65536 + e);
      s.x += v.x; s.y += v.y; s.z += v.z; s.w += v.w;
    }
    int lr = e >> 8, lc2 = e & 255;
    int row = mt * 256 + lr, col = nt * 256 + lc2;
    ushort4 o;
    o.x = (col < row) ? f2bf(s.x) : (ushort_t)0;
    o.y = (col + 1 < row) ? f2bf(s.y) : (ushort_t)0;
    o.z = (col + 2 < row) ? f2bf(s.z) : (ushort_t)0;
    o.w = (col + 3 < row) ? f2bf(s.w) : (ushort_t)0;
    *(ushort4*)(&ob[(size_t)row * L + col]) = o;
  }
}

// ---------- auxiliary kernels ----------
__global__ __launch_bounds__(256) void k_conv(const float* in, ushort_t* out, size_t n) {
  size_t i = ((size_t)blockIdx.x * 256 + threadIdx.x) * 4;
  if (i >= n) return;
  float4 v = *(const float4*)(in + i);
  out[i] = f2bf(v.x); out[i + 1] = f2bf(v.y); out[i + 2] = f2bf(v.z); out[i + 3] = f2bf(v.w);
}

__global__ __launch_bounds__(256) void k_tconv(const float* in, ushort_t* out, int R, int C) {
  __shared__ float t[32][33];
  int c0 = blockIdx.x * 32, r0 = blockIdx.y * 32;
  int tx = threadIdx.x & 31, ty = threadIdx.x >> 5;
#pragma unroll
  for (int i = ty; i < 32; i += 8) t[i][tx] = in[(size_t)(r0 + i) * C + c0 + tx];
  __syncthreads();
#pragma unroll
  for (int i = ty; i < 32; i += 8) out[(size_t)(c0 + i) * R + r0 + tx] = f2bf(t[tx][i]);
}

// fused weight prep: one f32 read -> straight bf16 copy + transposed bf16 copy
__global__ __launch_bounds__(256) void k_wprep(const float* in, ushort_t* outS, ushort_t* outT,
                                               int R, int C) {
  __shared__ float t[32][33];
  int c0 = blockIdx.x * 32, r0 = blockIdx.y * 32;
  int tx = threadIdx.x & 31, ty = threadIdx.x >> 5;
#pragma unroll
  for (int i = ty; i < 32; i += 8) {
    float v = in[(size_t)(r0 + i) * C + c0 + tx];
    t[i][tx] = v;
    outS[(size_t)(r0 + i) * C + c0 + tx] = f2bf(v);
  }
  __syncthreads();
#pragma unroll
  for (int i = ty; i < 32; i += 8) outT[(size_t)(c0 + i) * R + r0 + tx] = f2bf(t[tx][i]);
}

__global__ __launch_bounds__(256) void k_tb2b(const ushort_t* in, ushort_t* out, int L, int C) {
  __shared__ ushort_t t[32][33];
  int b = blockIdx.z;
  const ushort_t* ib = in + (size_t)b * L * C;
  ushort_t* ob = out + (size_t)b * C * L;
  int c0 = blockIdx.x * 32, l0 = blockIdx.y * 32;
  int tx = threadIdx.x & 31, ty = threadIdx.x >> 5;
#pragma unroll
  for (int i = ty; i < 32; i += 8) t[i][tx] = ib[(size_t)(l0 + i) * C + c0 + tx];
  __syncthreads();
#pragma unroll
  for (int i = ty; i < 32; i += 8) ob[(size_t)(c0 + i) * L + l0 + tx] = t[tx][i];
}

__device__ __forceinline__ void blockRed2(float& a, float& b, float* red) {
#pragma unroll
  for (int o = 32; o; o >>= 1) { a += __shfl_down(a, o); b += __shfl_down(b, o); }
  int w = threadIdx.x >> 6;
  if ((threadIdx.x & 63) == 0) { red[w] = a; red[4 + w] = b; }
  __syncthreads();
  a = red[0] + red[1] + red[2] + red[3];
  b = red[4] + red[5] + red[6] + red[7];
  __syncthreads();
}

// fused split-K combine + LN forward (H3 path)
__global__ __launch_bounds__(256) void k_lncomb(const float* part, const float* bias,
                                                const float* sc, const float* bi, float* nout,
                                                float* rstd, ushort_t* yb, size_t MN, int D,
                                                int S) {
  __shared__ float red[8];
  int row = blockIdx.x;
  int d = threadIdx.x * 4;
  size_t g = (size_t)row * D + d;
  float4 v = *(const float4*)(part + g);
  for (int s_ = 1; s_ < S; s_++) {
    float4 w = *(const float4*)(part + (size_t)s_ * MN + g);
    v.x += w.x; v.y += w.y; v.z += w.z; v.w += w.w;
  }
  float4 bb = *(const float4*)(bias + d);
  v.x += bb.x; v.y += bb.y; v.z += bb.z; v.w += bb.w;
  float s1 = v.x + v.y + v.z + v.w;
  float s2 = v.x * v.x + v.y * v.y + v.z * v.z + v.w * v.w;
  blockRed2(s1, s2, red);
  float mu = s1 / D;
  float var = s2 / D - mu * mu;
  float rs = rsqrtf(var + 1e-6f);
  float4 nv;
  nv.x = (v.x - mu) * rs; nv.y = (v.y - mu) * rs; nv.z = (v.z - mu) * rs; nv.w = (v.w - mu) * rs;
  *(float4*)(nout + g) = nv;
  float4 scv = *(const float4*)(sc + d);
  float4 biv = *(const float4*)(bi + d);
  ushort4 o;
  o.x = f2bf(nv.x * scv.x + biv.x);
  o.y = f2bf(nv.y * scv.y + biv.y);
  o.z = f2bf(nv.z * scv.z + biv.z);
  o.w = f2bf(nv.w * scv.w + biv.w);
  *(ushort4*)(yb + g) = o;
  if (threadIdx.x == 0) rstd[row] = rs;
}

// fused split-K combine + LN backward (G4 path): G4 = sum_s part[s];
// g3 = bf16(rstd*(dn - mean(dn) - n*mean(dn*n))), gsc = G4*n; also writes G4.
__global__ __launch_bounds__(256) void k_lnbwdc(const float* part, size_t MN, int S,
                                                const float* nn, const float* rstd,
                                                const float* sc, ushort_t* g3b, float* gsc,
                                                float* G4, int D) {
  __shared__ float red[8];
  int row = blockIdx.x;
  int d = threadIdx.x * 4;
  size_t g = (size_t)row * D + d;
  float4 v = *(const float4*)(part + g);
  for (int s_ = 1; s_ < S; s_++) {
    float4 w = *(const float4*)(part + (size_t)s_ * MN + g);
    v.x += w.x; v.y += w.y; v.z += w.z; v.w += w.w;
  }
  *(float4*)(G4 + g) = v;
  float4 n4 = *(const float4*)(nn + g);
  float4 s4 = *(const float4*)(sc + d);
  float dn0 = v.x * s4.x, dn1 = v.y * s4.y, dn2 = v.z * s4.z, dn3 = v.w * s4.w;
  float sa = dn0 + dn1 + dn2 + dn3;
  float sb = dn0 * n4.x + dn1 * n4.y + dn2 * n4.z + dn3 * n4.w;
  blockRed2(sa, sb, red);
  float a = sa / D, b = sb / D, rs = rstd[row];
  ushort4 o;
  o.x = f2bf(rs * (dn0 - a - n4.x * b));
  o.y = f2bf(rs * (dn1 - a - n4.y * b));
  o.z = f2bf(rs * (dn2 - a - n4.z * b));
  o.w = f2bf(rs * (dn3 - a - n4.w * b));
  *(ushort4*)(g3b + g) = o;
  float4 gv;
  gv.x = v.x * n4.x; gv.y = v.y * n4.y; gv.z = v.z * n4.z; gv.w = v.w * n4.w;
  *(float4*)(gsc + g) = gv;
}

__global__ __launch_bounds__(256) void k_lnfwd2(const float* X, const float* fs, const float* fb,
                                                ushort_t* yb, int D) {
  __shared__ float red[8];
  int row = blockIdx.x;
  const float* x = X + (size_t)row * D;
  float s = 0.f, s2 = 0.f;
  for (int d = threadIdx.x; d < D; d += 256) { float v = x[d]; s += v; s2 += v * v; }
  blockRed2(s, s2, red);
  float mu = s / D;
  float var = s2 / D - mu * mu;
  float rs = rsqrtf(var + 1e-6f);
  for (int d = threadIdx.x; d < D; d += 256) {
    size_t g = (size_t)row * D + d;
    float nv = (x[d] - mu) * rs;
    yb[g] = f2bf(nv * fs[g] + fb[g]);
  }
}

__global__ __launch_bounds__(256) void k_wsum(const float* w, float* o, int n) {
  __shared__ float red[4];
  float s = 0.f;
  for (int i = threadIdx.x; i < n; i += 256) s += w[i];
#pragma unroll
  for (int d = 32; d; d >>= 1) s += __shfl_down(s, d);
  if ((threadIdx.x & 63) == 0) red[threadIdx.x >> 6] = s;
  __syncthreads();
  if (threadIdx.x == 0) o[0] = fmaxf(red[0] + red[1] + red[2] + red[3], 1e-8f);
}

// register-staged fused softmax-grad: V=8192, 256 thr, 32 elem/thread in VGPRs.
__global__ __launch_bounds__(256) void k_softgrad(const ushort_t* logits, const float* labels,
                                                  const float* w, const float* wsum,
                                                  ushort_t* dlb, int V) {
  __shared__ float red[8];
  const int row = blockIdx.x;
  const int tid = threadIdx.x;
  const ushort_t* l = logits + (size_t)row * V + tid * 32;
  const float* y = labels + (size_t)row * V + tid * 32;
  float lv[32], yv[32];
#pragma unroll
  for (int i = 0; i < 4; i++) {
    us8 u = *reinterpret_cast<const us8*>(l + i * 8);
#pragma unroll
    for (int j = 0; j < 8; j++) lv[i * 8 + j] = bf2f(u[j]);
  }
#pragma unroll
  for (int i = 0; i < 8; i++) {
    float4 v = *reinterpret_cast<const float4*>(y + i * 4);
    yv[i * 4] = v.x; yv[i * 4 + 1] = v.y; yv[i * 4 + 2] = v.z; yv[i * 4 + 3] = v.w;
  }
  float m = lv[0], t = yv[0];
#pragma unroll
  for (int i = 1; i < 32; i++) { m = fmaxf(m, lv[i]); t += yv[i]; }
#pragma unroll
  for (int o = 32; o; o >>= 1) { m = fmaxf(m, __shfl_down(m, o)); t += __shfl_down(t, o); }
  int wv = tid >> 6;
  if ((tid & 63) == 0) { red[wv] = m; red[4 + wv] = t; }
  __syncthreads();
  m = fmaxf(fmaxf(red[0], red[1]), fmaxf(red[2], red[3]));
  t = red[4] + red[5] + red[6] + red[7];
  __syncthreads();
  float s = 0.f;
#pragma unroll
  for (int i = 0; i < 32; i++) { lv[i] = expf(lv[i] - m); s += lv[i]; }
#pragma unroll
  for (int o = 32; o; o >>= 1) s += __shfl_down(s, o);
  if ((tid & 63) == 0) red[wv] = s;
  __syncthreads();
  s = red[0] + red[1] + red[2] + red[3];
  float c = w[row] / wsum[0];
  float ci = c * t / s;
  ushort_t* dl = dlb + (size_t)row * V + tid * 32;
#pragma unroll
  for (int i = 0; i < 4; i++) {
    us8 o;
#pragma unroll
    for (int j = 0; j < 8; j++) o[j] = f2bf(ci * lv[i * 8 + j] - c * yv[i * 8 + j]);
    *reinterpret_cast<us8*>(dl + i * 8) = o;
  }
}

__global__ __launch_bounds__(256) void k_scanpart(const float* gs, const float* gb, float* ps,
                                                  float* pb, int L, int D) {
  int d = blockIdx.x * 256 + threadIdx.x;
  int seg = blockIdx.y, b = blockIdx.z;
  const int SEGL = L / 16;
  size_t base = ((size_t)b * L + seg * SEGL) * D + d;
  float s1 = 0.f, s2 = 0.f;
  for (int i = 0; i < SEGL; i++) { s1 += gs[base + (size_t)i * D]; s2 += gb[base + (size_t)i * D]; }
  size_t pi = ((size_t)b * 16 + seg) * D + d;
  ps[pi] = s1; pb[pi] = s2;
}

__global__ __launch_bounds__(256) void k_scanapply(const float* gs, const float* gb,
                                                   const float* ps, const float* pb,
                                                   const float* sc, const float* bi,
                                                   const float* steps, float* fs, float* fb,
                                                   int L, int D) {
  int d = blockIdx.x * 256 + threadIdx.x;
  int seg = blockIdx.y, b = blockIdx.z;
  const int SEGL = L / 16;
  float ss = steps[3];
  float rs_ = 0.f, rb_ = 0.f;
  for (int s = 0; s < seg; s++) {
    size_t pi = ((size_t)b * 16 + s) * D + d;
    rs_ += ps[pi]; rb_ += pb[pi];
  }
  float s0 = sc[d], b0 = bi[d];
  size_t base = ((size_t)b * L + seg * SEGL) * D + d;
  for (int i = 0; i < SEGL; i++) {
    size_t g = base + (size_t)i * D;
    fs[g] = s0 - ss * rs_;
    fb[g] = b0 - ss * rb_;
    rs_ += gs[g]; rb_ += gb[g];
  }
}

// ---------- orchestration ----------
extern "C" void kernel_launch(void* const* d_in, const int* in_sizes, int n_in, void* d_out,
                              int out_size, void* d_ws, size_t ws_size, hipStream_t stream) {
  const float* x        = (const float*)d_in[0];
  const float* labels   = (const float*)d_in[1];
  const float* weights  = (const float*)d_in[2];
  const float* W1       = (const float*)d_in[3];
  const float* b1       = (const float*)d_in[4];
  const float* W2       = (const float*)d_in[5];
  const float* b2       = (const float*)d_in[6];
  const float* ln_scale = (const float*)d_in[7];
  const float* ln_bias  = (const float*)d_in[8];
  const float* Wu       = (const float*)d_in[9];
  const float* bu       = (const float*)d_in[10];
  const float* steps    = (const float*)d_in[11];

  const int BL = in_sizes[2];   // 4096
  const int D  = in_sizes[7];   // 1024
  const int F  = in_sizes[4];   // 4096
  const int V  = in_sizes[10];  // 8192
  const int Bb = 2, L = BL / Bb;
  const int T2t = (L / 256) * (L / 256 + 1) / 2;   // 36 live 256-tri tiles
  const unsigned SMEM = 4 * 8192 * 2 * 2;          // 128 KB dynamic LDS

  char* ws = (char*)d_ws;
  size_t off = 0;
  auto take = [&](size_t b) { char* p = ws + off; off = (off + b + 255) & ~(size_t)255; return p; };

  ushort_t* xb   = (ushort_t*)take((size_t)BL * D * 2);
  ushort_t* w1t  = (ushort_t*)take((size_t)F * D * 2);
  ushort_t* w2t  = (ushort_t*)take((size_t)D * F * 2);
  ushort_t* w2b  = (ushort_t*)take((size_t)F * D * 2);
  ushort_t* wut  = (ushort_t*)take((size_t)V * D * 2);
  ushort_t* wub  = (ushort_t*)take((size_t)D * V * 2);
  ushort_t* H1b  = (ushort_t*)take((size_t)BL * F * 2);
  ushort_t* H2b  = (ushort_t*)take((size_t)BL * F * 2);
  float*    nbuf = (float*)take((size_t)BL * D * 4);
  float*    rstd = (float*)take((size_t)BL * 4);
  ushort_t* h4b  = (ushort_t*)take((size_t)BL * D * 2);
  float*    wsumb= (float*)take(256);
  float*    G4   = (float*)take((size_t)BL * D * 4);   // also g_bias
  float*    gsc  = (float*)take((size_t)BL * D * 4);   // g_scale
  ushort_t* g3b  = (ushort_t*)take((size_t)BL * D * 2);
  ushort_t* g3t  = (ushort_t*)take((size_t)BL * D * 2);
  float*    fs   = (float*)take((size_t)BL * D * 4);
  float*    fb   = (float*)take((size_t)BL * D * 4);
  ushort_t* x4b  = (ushort_t*)take((size_t)BL * D * 2);
  float*    psc  = (float*)take((size_t)Bb * 16 * D * 4);
  float*    pbi  = (float*)take((size_t)Bb * 16 * D * 4);
  // poolA (134MB): logitsb bf16 / split-K partials -> later {g1b, g1t, S1b, x2b}
  char* poolA = take((size_t)BL * V * 4);
  ushort_t* logitsb = (ushort_t*)poolA;
  float*    partA  = (float*)poolA;
  ushort_t* g1b = (ushort_t*)poolA;
  ushort_t* g1t = (ushort_t*)(poolA + (size_t)BL * F * 2);
  ushort_t* S1b = (ushort_t*)(poolA + (size_t)BL * F * 4);
  ushort_t* x2b = (ushort_t*)(poolA + (size_t)BL * F * 4 + (size_t)Bb * L * L * 2);
  // poolB (64MB): dlb bf16 -> later {S2b, X3, x3}; head hosts S1 partials (36MB)
  char* poolB = take((size_t)BL * V * 2);
  ushort_t* dlb = (ushort_t*)poolB;
  float*    partS1 = (float*)poolB;
  ushort_t* S2b = (ushort_t*)poolB;
  float*    X3  = (float*)(poolB + (size_t)Bb * L * L * 2);
  float*    x3  = (float*)(poolB + (size_t)Bb * L * L * 2 + (size_t)BL * D * 4);

  dim3 blk(256), blk5(512);
  const size_t MN_D = (size_t)BL * D;

  k_conv<<<dim3((unsigned)((size_t)BL * D / 1024)), blk, 0, stream>>>(x, xb, (size_t)BL * D);
  k_tconv<<<dim3(F / 32, D / 32), blk, 0, stream>>>(W1, w1t, D, F);
  k_wprep<<<dim3(D / 32, F / 32), blk, 0, stream>>>(W2, w2b, w2t, F, D);   // straight + (D,F)T
  k_wprep<<<dim3(V / 32, D / 32), blk, 0, stream>>>(Wu, wub, wut, D, V);   // straight + (V,D)T

  GemmP p;
  auto clr = [&]() { p = GemmP{}; };

  // 1) H1b = bf16(x@W1+b1) ; H2b = bf16(relu^2)
  clr(); p.A = xb; p.B = w1t; p.M = BL; p.N = F; p.K = D;
  p.outb = H1b; p.outb2 = H2b; p.bias = b1;
  gemm256<1><<<dim3(F / 256, BL / 256, 1), blk5, SMEM, stream>>>(p);
  // 2) H3 partials [split-K 4] -> fused combine+LN fwd
  clr(); p.A = H2b; p.B = w2t; p.M = BL; p.N = D; p.K = F;
  p.part = partA; p.ksplit = 4; p.Kc = F / 4;
  gemm256<6><<<dim3(D / 256, BL / 256, 4), blk5, SMEM, stream>>>(p);
  k_lncomb<<<dim3(BL), blk, 0, stream>>>(partA, b2, ln_scale, ln_bias, nbuf, rstd, h4b, MN_D, D, 4);
  // 4) logits = bf16(h4@Wu + bu)
  clr(); p.A = h4b; p.B = wut; p.M = BL; p.N = V; p.K = D; p.outb = logitsb; p.bias = bu;
  gemm256<8><<<dim3(V / 256, BL / 256, 1), blk5, SMEM, stream>>>(p);
  // 5) fused softmax grad (register-staged)
  k_wsum<<<dim3(1), blk, 0, stream>>>(weights, wsumb, BL);
  k_softgrad<<<dim3(BL), blk, 0, stream>>>(logitsb, labels, weights, wsumb, dlb, V);
  // 6) G4 partials [split-K 4] -> fused combine+LN bwd (writes G4, g3b, gsc)
  clr(); p.A = dlb; p.B = wub; p.M = BL; p.N = D; p.K = V;
  p.part = partA; p.ksplit = 4; p.Kc = V / 4;
  gemm256<6><<<dim3(D / 256, BL / 256, 4), blk5, SMEM, stream>>>(p);
  k_lnbwdc<<<dim3(BL), blk, 0, stream>>>(partA, MN_D, 4, nbuf, rstd, ln_scale, g3b, gsc, G4, D);
  // 8) g1 = (g3 @ W2^T) * 2*sqrt(H2)
  clr(); p.A = g3b; p.B = w2b; p.M = BL; p.N = F; p.K = D; p.outb = g1b; p.auxb = H2b;
  gemm256<2><<<dim3(F / 256, BL / 256, 1), blk5, SMEM, stream>>>(p);
  // 9) transposes for attention V-operands
  k_tb2b<<<dim3(F / 32, L / 32, Bb), blk, 0, stream>>>(g1b, g1t, L, F);
  k_tb2b<<<dim3(D / 32, L / 32, Bb), blk, 0, stream>>>(g3b, g3t, L, D);
  // 10) S1 = tril(x x^T, -1)   [split-K 2, compact-tri, partials in poolB]
  clr(); p.A = xb; p.B = xb; p.M = L; p.N = L; p.K = D;
  p.sA = (long long)L * D; p.sB = (long long)L * D;
  p.part = partS1; p.ksplit = 2; p.Kc = D / 2; p.Tt = T2t;
  gemm256<7><<<dim3(T2t, 1, Bb * 2), blk5, SMEM, stream>>>(p);
  k_combtri<<<dim3(T2t, Bb), blk, 0, stream>>>(partS1, S1b, T2t, 2, L);
  // 11) x2 = relu(H1 - ss0 * S1@g1)^2   [K-limited, aux = bf16 H1b]
  clr(); p.A = S1b; p.B = g1t; p.M = L; p.N = F; p.K = L;
  p.sA = (long long)L * L; p.sB = (long long)F * L;
  p.outb = x2b; p.sOutB = (long long)L * F; p.auxb = H1b; p.sAuxF = (long long)L * F;
  p.steps = steps;
  gemm256<4><<<dim3(F / 256, L / 256, Bb), blk5, SMEM, stream>>>(p);
  // 12) X3 = x2@W2 + b2   [split-K 4]
  clr(); p.A = x2b; p.B = w2t; p.M = BL; p.N = D; p.K = F;
  p.part = partA; p.ksplit = 4; p.Kc = F / 4;
  gemm256<6><<<dim3(D / 256, BL / 256, 4), blk5, SMEM, stream>>>(p);
  k_comb<<<dim3((unsigned)(MN_D / 1024)), blk, 0, stream>>>(partA, b2, X3, D, MN_D, 4);
  // 13) S2 = tril(x2 H2^T, -1)   [split-K 4, compact-tri]
  clr(); p.A = x2b; p.B = H2b; p.M = L; p.N = L; p.K = F;
  p.sA = (long long)L * F; p.sB = (long long)L * F;
  p.part = partA; p.ksplit = 4; p.Kc = F / 4; p.Tt = T2t;
  gemm256<7><<<dim3(T2t, 1, Bb * 4), blk5, SMEM, stream>>>(p);
  k_combtri<<<dim3(T2t, Bb), blk, 0, stream>>>(partA, S2b, T2t, 4, L);
  // 14) x3 = X3 - ss2 * S2@g3   [K-limited, 128^2 kernel for grid size]
  clr(); p.A = S2b; p.B = g3t; p.M = L; p.N = D; p.K = L;
  p.sA = (long long)L * L; p.sB = (long long)D * L;
  p.outf = x3; p.sOutF = (long long)L * D; p.auxf = X3; p.sAuxF = (long long)L * D; p.steps = steps;
  gemm_bt<5><<<dim3(D / 128, L / 128, Bb), blk, 0, stream>>>(p);
  // 15) exclusive cumsums -> fast_scale / fast_bias
  k_scanpart<<<dim3(D / 256, 16, Bb), blk, 0, stream>>>(gsc, G4, psc, pbi, L, D);
  k_scanapply<<<dim3(D / 256, 16, Bb), blk, 0, stream>>>(gsc, G4, psc, pbi, ln_scale, ln_bias,
                                                         steps, fs, fb, L, D);
  // 16) x4 = LN(x3)*fast_scale + fast_bias
  k_lnfwd2<<<dim3(BL), blk, 0, stream>>>(x3, fs, fb, x4b, D);
  // 17) out = x4@Wu + bu
  clr(); p.A = x4b; p.B = wut; p.M = BL; p.N = V; p.K = D; p.outf = (float*)d_out; p.bias = bu;
  gemm256<0><<<dim3(V / 256, BL / 256, 1), blk5, SMEM, stream>>>(p);
}

// Round 14
// 1020.334 us; speedup vs baseline: 1.0861x; 1.0525x over previous
//
#include <hip/hip_runtime.h>
#include <cstdint>

typedef unsigned short ushort_t;
typedef __bf16 bf16x8 __attribute__((ext_vector_type(8)));
typedef float f32x4 __attribute__((ext_vector_type(4)));
typedef ushort_t us8 __attribute__((ext_vector_type(8)));

// ---------- helpers ----------
__device__ __forceinline__ ushort_t f2bf(float f) {
  union { float f; unsigned int u; } v; v.f = f;
  unsigned int u = v.u;
  unsigned int r = (u + 0x7fffu + ((u >> 16) & 1u)) >> 16;
  return (ushort_t)r;
}
__device__ __forceinline__ float bf2f(ushort_t u) {
  union { unsigned int u; float f; } v; v.u = ((unsigned int)u) << 16; return v.f;
}

#define GLOAD16(gp, lp)                                                              \
  __builtin_amdgcn_global_load_lds(                                                  \
      reinterpret_cast<const __attribute__((address_space(1))) unsigned int*>(       \
          reinterpret_cast<uintptr_t>(gp)),                                          \
      reinterpret_cast<__attribute__((address_space(3))) unsigned int*>(             \
          reinterpret_cast<uintptr_t>(lp)),                                          \
      16, 0, 0)

// EPI: 0 = outf = acc + bias (nontemporal)       (out)
//      8 = outb = bf16(acc + bias)               (logits)
//      1 = outb = bf16(acc+bias); outb2 = bf16(relu^2)    (H1b + H2b)
//      2 = outb = bf16(acc * 2*sqrt(auxb))       (g1)
//      4 = outb = bf16(relu(bf2f(auxb) - ss0*acc)^2); K-limit  (x2)
//      5 = outf = (sum_s part[s] + bias) - ss2*acc; K-limit    (x3, fused X3-combine)
//      6 = split-K partial, full-matrix f32      (H3, G4, X3 stage 1)
//      7 = split-K partial, compact-tri grid, 256x256 tiles   (S1, S2 stage 1)
struct GemmP {
  const ushort_t* A; const ushort_t* B;
  int M, N, K;
  long long sA, sB;
  float* outf;   long long sOutF;
  ushort_t* outb; long long sOutB;
  ushort_t* outb2;
  const float* bias;
  const float* auxf; long long sAuxF;   // EPI5: sAuxF = partial slice stride (MN)
  const ushort_t* auxb;
  const float* steps;
  float* part; int ksplit, Kc, Tt;
};

// XCD slab swizzle (validated R13: FETCH 135->49MB on the out GEMM): when
// gridDim.x%8==0, each XCD owns an nt-slab of gx/8 columns x ALL mt rows ->
// per-XCD B working set <= ~2MB, L2-RESIDENT. Bijective. Fallback: m204.
__device__ __forceinline__ void tile_map(int& mt, int& nt) {
  const int orig = blockIdx.y * gridDim.x + blockIdx.x;
  const int gx = gridDim.x;
  if ((gx & 7) == 0) {
    const int slab = gx >> 3;
    const int xcd = orig & 7, loc = orig >> 3;
    nt = xcd * slab + loc % slab;
    mt = loc / slab;
  } else {
    const int nwg = gx * gridDim.y;
    const int xcd = orig & 7, loc = orig >> 3;
    const int q8 = nwg >> 3, r8 = nwg & 7;
    const int wg = (xcd < r8) ? (xcd * (q8 + 1) + loc) : (r8 * (q8 + 1) + (xcd - r8) * q8 + loc);
    nt = wg % gx; mt = wg / gx;
  }
}
__device__ __forceinline__ int tri_wg() {   // m204 bijective over tri grid
  const int orig = blockIdx.y * gridDim.x + blockIdx.x;
  const int nwg = gridDim.x * gridDim.y;
  const int xcd = orig & 7, loc = orig >> 3;
  const int q8 = nwg >> 3, r8 = nwg & 7;
  return (xcd < r8) ? (xcd * (q8 + 1) + loc) : (r8 * (q8 + 1) + (xcd - r8) * q8 + loc);
}

// ---------- 256x256 GEMM (R9-proven): 8 waves, BK=32, 4-buf depth-3 ----------
template <int EPI>
__global__ __launch_bounds__(512, 2) void gemm256(GemmP p) {
  int mt, nt;
  int wg = 0;
  if (EPI == 7) {            // compact lower-tri tile index -> (mt, nt)
    wg = tri_wg();
    int t_ = wg;
    mt = (int)((sqrtf(8.f * t_ + 1.f) - 1.f) * 0.5f);
    while ((mt + 1) * (mt + 2) / 2 <= t_) mt++;
    while (mt * (mt + 1) / 2 > t_) mt--;
    nt = t_ - mt * (mt + 1) / 2;
  } else {
    tile_map(mt, nt);
  }
  const int m0 = mt * 256, n0 = nt * 256;

  int bz = blockIdx.z, ks = 0;
  if (EPI == 6 || EPI == 7) { bz = blockIdx.z / p.ksplit; ks = blockIdx.z % p.ksplit; }

  const ushort_t* A = p.A + (size_t)bz * p.sA;
  const ushort_t* B = p.B + (size_t)bz * p.sB;

  int kbeg = 0, kend = p.K;
  if (EPI == 6 || EPI == 7) { kbeg = ks * p.Kc; kend = kbeg + p.Kc; }
  else if (EPI == 4) kend = min(p.K, m0 + 256);

  extern __shared__ ushort_t smem[];      // 4 bufs x (16KB A + 16KB B) = 128KB
  ushort_t* sA = smem;
  ushort_t* sB = smem + 4 * 8192;

  const int tid = threadIdx.x;
  const int wid = tid >> 6, lane = tid & 63;
  const int wm = wid >> 2, wn = wid & 3;

  f32x4 acc[8][4];
#pragma unroll
  for (int i = 0; i < 8; i++)
#pragma unroll
    for (int j = 0; j < 4; j++) acc[i][j] = f32x4{0.f, 0.f, 0.f, 0.f};

  const int lr = lane >> 2;
  const int lcsw = (((lane & 3) ^ ((lr >> 1) & 3)) * 8);
  const int rT0 = wid * 16 + lr;
  const int rT1 = 128 + wid * 16 + lr;
  const ushort_t* gA0 = A + (size_t)(m0 + rT0) * p.K + lcsw;
  const ushort_t* gA1 = A + (size_t)(m0 + rT1) * p.K + lcsw;
  const ushort_t* gB0 = B + (size_t)(n0 + rT0) * p.K + lcsw;
  const ushort_t* gB1 = B + (size_t)(n0 + rT1) * p.K + lcsw;
  ushort_t* lA0 = &sA[wid * 512];
  ushort_t* lA1 = &sA[(8 + wid) * 512];
  ushort_t* lB0 = &sB[wid * 512];
  ushort_t* lB1 = &sB[(8 + wid) * 512];

  const int fr = lane & 15;
  const int q = lane >> 4;
  const int slot = (q ^ ((fr >> 1) & 3)) * 8;
  int offA[8], offB[4];
#pragma unroll
  for (int i = 0; i < 8; i++) offA[i] = (wm * 8 + i) * 512 + fr * 32 + slot;
#pragma unroll
  for (int j = 0; j < 4; j++) offB[j] = (wn * 4 + j) * 512 + fr * 32 + slot;

  const int nT = (kend - kbeg) >> 5;    // BK = 32
  auto stage4 = [&](int t) {
    const int kk = kbeg + t * 32;
    const int o = (t & 3) * 8192;
    GLOAD16(gA0 + kk, lA0 + o);
    GLOAD16(gA1 + kk, lA1 + o);
    GLOAD16(gB0 + kk, lB0 + o);
    GLOAD16(gB1 + kk, lB1 + o);
  };
  stage4(0);
  if (nT > 1) stage4(1);
  if (nT > 2) stage4(2);
  if (nT > 2)      { asm volatile("s_waitcnt vmcnt(8)" ::: "memory"); }
  else if (nT > 1) { asm volatile("s_waitcnt vmcnt(4)" ::: "memory"); }
  else             { asm volatile("s_waitcnt vmcnt(0)" ::: "memory"); }
  __builtin_amdgcn_s_barrier();

  for (int t = 0; t < nT; ++t) {
    const int co = (t & 3) * 8192;
    if (t + 3 < nT) stage4(t + 3);
    __builtin_amdgcn_sched_barrier(0);
    bf16x8 av[8], bv[4];
#pragma unroll
    for (int j = 0; j < 4; j++) bv[j] = *reinterpret_cast<const bf16x8*>(&sB[co + offB[j]]);
#pragma unroll
    for (int i = 0; i < 8; i++) av[i] = *reinterpret_cast<const bf16x8*>(&sA[co + offA[i]]);
    __builtin_amdgcn_s_setprio(1);
#pragma unroll
    for (int i = 0; i < 8; i++)
#pragma unroll
      for (int j = 0; j < 4; j++)
        acc[i][j] = __builtin_amdgcn_mfma_f32_16x16x32_bf16(av[i], bv[j], acc[i][j], 0, 0, 0);
    __builtin_amdgcn_s_setprio(0);
    if (t + 3 < nT)      { asm volatile("s_waitcnt vmcnt(8)" ::: "memory"); }
    else if (t + 2 < nT) { asm volatile("s_waitcnt vmcnt(4)" ::: "memory"); }
    else if (t + 1 < nT) { asm volatile("s_waitcnt vmcnt(0)" ::: "memory"); }
    __builtin_amdgcn_s_barrier();
  }

  const int fq = q;
  float ss = 0.f;
  if (EPI == 4) ss = p.steps[0];
  float* outf = p.outf ? p.outf + (size_t)bz * p.sOutF : nullptr;
  ushort_t* outb = p.outb ? p.outb + (size_t)bz * p.sOutB : nullptr;
  ushort_t* outb2 = p.outb2;
  const ushort_t* auxb = p.auxb ? p.auxb + (size_t)bz * p.sAuxF : nullptr;
  float* partT = nullptr;
  if (EPI == 6) partT = p.part + (size_t)blockIdx.z * p.M * p.N;
  if (EPI == 7) partT = p.part + ((size_t)blockIdx.z * p.Tt + wg) * 65536;

#pragma unroll
  for (int i = 0; i < 8; i++) {
#pragma unroll
    for (int j = 0; j < 4; j++) {
#pragma unroll
      for (int r2 = 0; r2 < 4; r2++) {
        int lrow = wm * 128 + i * 16 + fq * 4 + r2;
        int lcol = wn * 64 + j * 16 + fr;
        int row = m0 + lrow, col = n0 + lcol;
        size_t g = (size_t)row * p.N + col;
        float v = acc[i][j][r2];
        if (EPI == 0) {
          __builtin_nontemporal_store(v + p.bias[col], &outf[g]);
        } else if (EPI == 8) {
          outb[g] = f2bf(v + p.bias[col]);
        } else if (EPI == 1) {
          v += p.bias[col];
          outb[g] = f2bf(v);
          float rl = fmaxf(v, 0.f);
          outb2[g] = f2bf(rl * rl);
        } else if (EPI == 2) {
          outb[g] = f2bf(v * 2.f * sqrtf(bf2f(auxb[g])));
        } else if (EPI == 4) {
          float x1 = bf2f(auxb[g]) - ss * v;
          float rl = fmaxf(x1, 0.f);
          outb[g] = f2bf(rl * rl);
        } else if (EPI == 6) {
          partT[g] = v;
        } else if (EPI == 7) {
          partT[lrow * 256 + lcol] = v;
        }
      }
    }
  }
}

// ---------- 128x128 GEMM (R9-proven) -- x3 (EPI 5, fused X3-combine) ----------
template <int EPI>
__global__ __launch_bounds__(256) void gemm_bt(GemmP p) {
  int mt, nt;
  tile_map(mt, nt);
  const int m0 = mt * 128, n0 = nt * 128;
  const int bz = blockIdx.z;

  const ushort_t* A = p.A + (size_t)bz * p.sA;
  const ushort_t* B = p.B + (size_t)bz * p.sB;

  int kend = p.K;
  if (EPI == 5) kend = min(p.K, m0 + 128);

  __shared__ ushort_t sA[4 * 128 * 32];
  __shared__ ushort_t sB[4 * 128 * 32];

  const int tid = threadIdx.x;
  const int wid = tid >> 6, lane = tid & 63;
  const int wm = wid >> 1, wn = wid & 1;

  f32x4 acc[4][4];
#pragma unroll
  for (int i = 0; i < 4; i++)
#pragma unroll
    for (int j = 0; j < 4; j++) acc[i][j] = f32x4{0.f, 0.f, 0.f, 0.f};

  const int lr = lane >> 2;
  const int lc = (lane & 3) * 8;
  const int rA0 = wid * 16 + lr;
  const int rA1 = 64 + wid * 16 + lr;
  const ushort_t* gA0 = A + (size_t)(m0 + rA0) * p.K + lc;
  const ushort_t* gA1 = A + (size_t)(m0 + rA1) * p.K + lc;
  const ushort_t* gB0 = B + (size_t)(n0 + rA0) * p.K + lc;
  const ushort_t* gB1 = B + (size_t)(n0 + rA1) * p.K + lc;
  ushort_t* lA0 = &sA[wid * 512];
  ushort_t* lA1 = &sA[(4 + wid) * 512];
  ushort_t* lB0 = &sB[wid * 512];
  ushort_t* lB1 = &sB[(4 + wid) * 512];

  const int fr = lane & 15;
  const int kb = (lane >> 4) * 8;

  const int nIter = kend >> 5;
  auto stage = [&](int t) {
    const int kk = t * 32;
    const int o = (t & 3) * 4096;
    GLOAD16(gA0 + kk, lA0 + o);
    GLOAD16(gA1 + kk, lA1 + o);
    GLOAD16(gB0 + kk, lB0 + o);
    GLOAD16(gB1 + kk, lB1 + o);
  };
  stage(0);
  if (nIter > 1) stage(1);
  if (nIter > 2) stage(2);
  if (nIter > 2)      { asm volatile("s_waitcnt vmcnt(8)" ::: "memory"); }
  else if (nIter > 1) { asm volatile("s_waitcnt vmcnt(4)" ::: "memory"); }
  else                { asm volatile("s_waitcnt vmcnt(0)" ::: "memory"); }
  __builtin_amdgcn_s_barrier();

  for (int t = 0; t < nIter; ++t) {
    const int co = (t & 3) * 4096;
    if (t + 3 < nIter) stage(t + 3);
    __builtin_amdgcn_sched_barrier(0);
    bf16x8 av[4], bv[4];
#pragma unroll
    for (int i = 0; i < 4; i++) {
      av[i] = *reinterpret_cast<const bf16x8*>(&sA[co + (wm * 64 + i * 16 + fr) * 32 + kb]);
      bv[i] = *reinterpret_cast<const bf16x8*>(&sB[co + (wn * 64 + i * 16 + fr) * 32 + kb]);
    }
    __builtin_amdgcn_s_setprio(1);
#pragma unroll
    for (int i = 0; i < 4; i++)
#pragma unroll
      for (int j = 0; j < 4; j++)
        acc[i][j] = __builtin_amdgcn_mfma_f32_16x16x32_bf16(av[i], bv[j], acc[i][j], 0, 0, 0);
    __builtin_amdgcn_s_setprio(0);
    if (t + 3 < nIter)      { asm volatile("s_waitcnt vmcnt(8)" ::: "memory"); }
    else if (t + 2 < nIter) { asm volatile("s_waitcnt vmcnt(4)" ::: "memory"); }
    else if (t + 1 < nIter) { asm volatile("s_waitcnt vmcnt(0)" ::: "memory"); }
    __builtin_amdgcn_s_barrier();
  }

  const int fq = lane >> 4;
  float ss = (EPI == 5) ? p.steps[2] : 0.f;
  float* outf = p.outf ? p.outf + (size_t)bz * p.sOutF : nullptr;

#pragma unroll
  for (int i = 0; i < 4; i++) {
#pragma unroll
    for (int j = 0; j < 4; j++) {
#pragma unroll
      for (int r2 = 0; r2 < 4; r2++) {
        int row = m0 + wm * 64 + i * 16 + fq * 4 + r2;
        int col = n0 + wn * 64 + j * 16 + fr;
        size_t g = (size_t)row * p.N + col;
        float v = acc[i][j][r2];
        if (EPI == 5) {
          // fused X3-combine: x3 = (sum_s part[s] + b2) - ss2 * (S2@g3)
          size_t gp = (size_t)(bz * p.M + row) * p.N + col;
          float sum = p.bias[col];
#pragma unroll
          for (int s_ = 0; s_ < 4; s_++) sum += p.part[(size_t)s_ * p.sAuxF + gp];
          outf[g] = sum - ss * v;
        } else {
          outf[g] = v + (p.bias ? p.bias[col] : 0.f);
        }
      }
    }
  }
}

// 256x256 compact-tri combine: S_bf16 = tril(sum_s part[s], -1)
__global__ __launch_bounds__(256) void k_combtri(const float* part, ushort_t* out, int Tt, int S,
                                                 int L) {
  int t = blockIdx.x, bz = blockIdx.y;
  int mt = (int)((sqrtf(8.f * t + 1.f) - 1.f) * 0.5f);
  while ((mt + 1) * (mt + 2) / 2 <= t) mt++;
  while (mt * (mt + 1) / 2 > t) mt--;
  int nt = t - mt * (mt + 1) / 2;
  const float* pb = part + ((size_t)bz * S * Tt + t) * 65536;
  ushort_t* ob = out + (size_t)bz * L * L;
  for (int e4 = threadIdx.x; e4 < 16384; e4 += 256) {
    int e = e4 * 4;
    float4 s = *(const float4*)(pb + e);
    for (int p_ = 1; p_ < S; p_++) {
      float4 v = *(const float4*)(pb + (size_t)p_ * Tt * 65536 + e);
      s.x += v.x; s.y += v.y; s.z += v.z; s.w += v.w;
    }
    int lr = e >> 8, lc2 = e & 255;
    int row = mt * 256 + lr, col = nt * 256 + lc2;
    ushort4 o;
    o.x = (col < row) ? f2bf(s.x) : (ushort_t)0;
    o.y = (col + 1 < row) ? f2bf(s.y) : (ushort_t)0;
    o.z = (col + 2 < row) ? f2bf(s.z) : (ushort_t)0;
    o.w = (col + 3 < row) ? f2bf(s.w) : (ushort_t)0;
    *(ushort4*)(&ob[(size_t)row * L + col]) = o;
  }
}

// ---------- auxiliary kernels ----------
__global__ __launch_bounds__(256) void k_conv(const float* in, ushort_t* out, size_t n) {
  size_t i = ((size_t)blockIdx.x * 256 + threadIdx.x) * 4;
  if (i >= n) return;
  float4 v = *(const float4*)(in + i);
  out[i] = f2bf(v.x); out[i + 1] = f2bf(v.y); out[i + 2] = f2bf(v.z); out[i + 3] = f2bf(v.w);
}

__global__ __launch_bounds__(256) void k_tconv(const float* in, ushort_t* out, int R, int C) {
  __shared__ float t[32][33];
  int c0 = blockIdx.x * 32, r0 = blockIdx.y * 32;
  int tx = threadIdx.x & 31, ty = threadIdx.x >> 5;
#pragma unroll
  for (int i = ty; i < 32; i += 8) t[i][tx] = in[(size_t)(r0 + i) * C + c0 + tx];
  __syncthreads();
#pragma unroll
  for (int i = ty; i < 32; i += 8) out[(size_t)(c0 + i) * R + r0 + tx] = f2bf(t[tx][i]);
}

// fused weight prep: one f32 read -> straight bf16 copy + transposed bf16 copy
__global__ __launch_bounds__(256) void k_wprep(const float* in, ushort_t* outS, ushort_t* outT,
                                               int R, int C) {
  __shared__ float t[32][33];
  int c0 = blockIdx.x * 32, r0 = blockIdx.y * 32;
  int tx = threadIdx.x & 31, ty = threadIdx.x >> 5;
#pragma unroll
  for (int i = ty; i < 32; i += 8) {
    float v = in[(size_t)(r0 + i) * C + c0 + tx];
    t[i][tx] = v;
    outS[(size_t)(r0 + i) * C + c0 + tx] = f2bf(v);
  }
  __syncthreads();
#pragma unroll
  for (int i = ty; i < 32; i += 8) outT[(size_t)(c0 + i) * R + r0 + tx] = f2bf(t[tx][i]);
}

__global__ __launch_bounds__(256) void k_tb2b(const ushort_t* in, ushort_t* out, int L, int C) {
  __shared__ ushort_t t[32][33];
  int b = blockIdx.z;
  const ushort_t* ib = in + (size_t)b * L * C;
  ushort_t* ob = out + (size_t)b * C * L;
  int c0 = blockIdx.x * 32, l0 = blockIdx.y * 32;
  int tx = threadIdx.x & 31, ty = threadIdx.x >> 5;
#pragma unroll
  for (int i = ty; i < 32; i += 8) t[i][tx] = ib[(size_t)(l0 + i) * C + c0 + tx];
  __syncthreads();
#pragma unroll
  for (int i = ty; i < 32; i += 8) ob[(size_t)(c0 + i) * L + l0 + tx] = t[tx][i];
}

__device__ __forceinline__ void blockRed2(float& a, float& b, float* red) {
#pragma unroll
  for (int o = 32; o; o >>= 1) { a += __shfl_down(a, o); b += __shfl_down(b, o); }
  int w = threadIdx.x >> 6;
  if ((threadIdx.x & 63) == 0) { red[w] = a; red[4 + w] = b; }
  __syncthreads();
  a = red[0] + red[1] + red[2] + red[3];
  b = red[4] + red[5] + red[6] + red[7];
  __syncthreads();
}

// fused split-K combine + LN forward (H3 path)
__global__ __launch_bounds__(256) void k_lncomb(const float* part, const float* bias,
                                                const float* sc, const float* bi, float* nout,
                                                float* rstd, ushort_t* yb, size_t MN, int D,
                                                int S) {
  __shared__ float red[8];
  int row = blockIdx.x;
  int d = threadIdx.x * 4;
  size_t g = (size_t)row * D + d;
  float4 v = *(const float4*)(part + g);
  for (int s_ = 1; s_ < S; s_++) {
    float4 w = *(const float4*)(part + (size_t)s_ * MN + g);
    v.x += w.x; v.y += w.y; v.z += w.z; v.w += w.w;
  }
  float4 bb = *(const float4*)(bias + d);
  v.x += bb.x; v.y += bb.y; v.z += bb.z; v.w += bb.w;
  float s1 = v.x + v.y + v.z + v.w;
  float s2 = v.x * v.x + v.y * v.y + v.z * v.z + v.w * v.w;
  blockRed2(s1, s2, red);
  float mu = s1 / D;
  float var = s2 / D - mu * mu;
  float rs = rsqrtf(var + 1e-6f);
  float4 nv;
  nv.x = (v.x - mu) * rs; nv.y = (v.y - mu) * rs; nv.z = (v.z - mu) * rs; nv.w = (v.w - mu) * rs;
  *(float4*)(nout + g) = nv;
  float4 scv = *(const float4*)(sc + d);
  float4 biv = *(const float4*)(bi + d);
  ushort4 o;
  o.x = f2bf(nv.x * scv.x + biv.x);
  o.y = f2bf(nv.y * scv.y + biv.y);
  o.z = f2bf(nv.z * scv.z + biv.z);
  o.w = f2bf(nv.w * scv.w + biv.w);
  *(ushort4*)(yb + g) = o;
  if (threadIdx.x == 0) rstd[row] = rs;
}

// fused split-K combine + LN backward (G4 path)
__global__ __launch_bounds__(256) void k_lnbwdc(const float* part, size_t MN, int S,
                                                const float* nn, const float* rstd,
                                                const float* sc, ushort_t* g3b, float* gsc,
                                                float* G4, int D) {
  __shared__ float red[8];
  int row = blockIdx.x;
  int d = threadIdx.x * 4;
  size_t g = (size_t)row * D + d;
  float4 v = *(const float4*)(part + g);
  for (int s_ = 1; s_ < S; s_++) {
    float4 w = *(const float4*)(part + (size_t)s_ * MN + g);
    v.x += w.x; v.y += w.y; v.z += w.z; v.w += w.w;
  }
  *(float4*)(G4 + g) = v;
  float4 n4 = *(const float4*)(nn + g);
  float4 s4 = *(const float4*)(sc + d);
  float dn0 = v.x * s4.x, dn1 = v.y * s4.y, dn2 = v.z * s4.z, dn3 = v.w * s4.w;
  float sa = dn0 + dn1 + dn2 + dn3;
  float sb = dn0 * n4.x + dn1 * n4.y + dn2 * n4.z + dn3 * n4.w;
  blockRed2(sa, sb, red);
  float a = sa / D, b = sb / D, rs = rstd[row];
  ushort4 o;
  o.x = f2bf(rs * (dn0 - a - n4.x * b));
  o.y = f2bf(rs * (dn1 - a - n4.y * b));
  o.z = f2bf(rs * (dn2 - a - n4.z * b));
  o.w = f2bf(rs * (dn3 - a - n4.w * b));
  *(ushort4*)(g3b + g) = o;
  float4 gv;
  gv.x = v.x * n4.x; gv.y = v.y * n4.y; gv.z = v.z * n4.z; gv.w = v.w * n4.w;
  *(float4*)(gsc + g) = gv;
}

__global__ __launch_bounds__(256) void k_lnfwd2(const float* X, const float* fs, const float* fb,
                                                ushort_t* yb, int D) {
  __shared__ float red[8];
  int row = blockIdx.x;
  const float* x = X + (size_t)row * D;
  float s = 0.f, s2 = 0.f;
  for (int d = threadIdx.x; d < D; d += 256) { float v = x[d]; s += v; s2 += v * v; }
  blockRed2(s, s2, red);
  float mu = s / D;
  float var = s2 / D - mu * mu;
  float rs = rsqrtf(var + 1e-6f);
  for (int d = threadIdx.x; d < D; d += 256) {
    size_t g = (size_t)row * D + d;
    float nv = (x[d] - mu) * rs;
    yb[g] = f2bf(nv * fs[g] + fb[g]);
  }
}

__global__ __launch_bounds__(256) void k_wsum(const float* w, float* o, int n) {
  __shared__ float red[4];
  float s = 0.f;
  for (int i = threadIdx.x; i < n; i += 256) s += w[i];
#pragma unroll
  for (int d = 32; d; d >>= 1) s += __shfl_down(s, d);
  if ((threadIdx.x & 63) == 0) red[threadIdx.x >> 6] = s;
  __syncthreads();
  if (threadIdx.x == 0) o[0] = fmaxf(red[0] + red[1] + red[2] + red[3], 1e-8f);
}

// register-staged fused softmax-grad: V=8192, 256 thr, 32 elem/thread in VGPRs.
__global__ __launch_bounds__(256) void k_softgrad(const ushort_t* logits, const float* labels,
                                                  const float* w, const float* wsum,
                                                  ushort_t* dlb, int V) {
  __shared__ float red[8];
  const int row = blockIdx.x;
  const int tid = threadIdx.x;
  const ushort_t* l = logits + (size_t)row * V + tid * 32;
  const float* y = labels + (size_t)row * V + tid * 32;
  float lv[32], yv[32];
#pragma unroll
  for (int i = 0; i < 4; i++) {
    us8 u = *reinterpret_cast<const us8*>(l + i * 8);
#pragma unroll
    for (int j = 0; j < 8; j++) lv[i * 8 + j] = bf2f(u[j]);
  }
#pragma unroll
  for (int i = 0; i < 8; i++) {
    float4 v = *reinterpret_cast<const float4*>(y + i * 4);
    yv[i * 4] = v.x; yv[i * 4 + 1] = v.y; yv[i * 4 + 2] = v.z; yv[i * 4 + 3] = v.w;
  }
  float m = lv[0], t = yv[0];
#pragma unroll
  for (int i = 1; i < 32; i++) { m = fmaxf(m, lv[i]); t += yv[i]; }
#pragma unroll
  for (int o = 32; o; o >>= 1) { m = fmaxf(m, __shfl_down(m, o)); t += __shfl_down(t, o); }
  int wv = tid >> 6;
  if ((tid & 63) == 0) { red[wv] = m; red[4 + wv] = t; }
  __syncthreads();
  m = fmaxf(fmaxf(red[0], red[1]), fmaxf(red[2], red[3]));
  t = red[4] + red[5] + red[6] + red[7];
  __syncthreads();
  float s = 0.f;
#pragma unroll
  for (int i = 0; i < 32; i++) { lv[i] = expf(lv[i] - m); s += lv[i]; }
#pragma unroll
  for (int o = 32; o; o >>= 1) s += __shfl_down(s, o);
  if ((tid & 63) == 0) red[wv] = s;
  __syncthreads();
  s = red[0] + red[1] + red[2] + red[3];
  float c = w[row] / wsum[0];
  float ci = c * t / s;
  ushort_t* dl = dlb + (size_t)row * V + tid * 32;
#pragma unroll
  for (int i = 0; i < 4; i++) {
    us8 o;
#pragma unroll
    for (int j = 0; j < 8; j++) o[j] = f2bf(ci * lv[i * 8 + j] - c * yv[i * 8 + j]);
    *reinterpret_cast<us8*>(dl + i * 8) = o;
  }
}

__global__ __launch_bounds__(256) void k_scanpart(const float* gs, const float* gb, float* ps,
                                                  float* pb, int L, int D) {
  int d = blockIdx.x * 256 + threadIdx.x;
  int seg = blockIdx.y, b = blockIdx.z;
  const int SEGL = L / 16;
  size_t base = ((size_t)b * L + seg * SEGL) * D + d;
  float s1 = 0.f, s2 = 0.f;
  for (int i = 0; i < SEGL; i++) { s1 += gs[base + (size_t)i * D]; s2 += gb[base + (size_t)i * D]; }
  size_t pi = ((size_t)b * 16 + seg) * D + d;
  ps[pi] = s1; pb[pi] = s2;
}

__global__ __launch_bounds__(256) void k_scanapply(const float* gs, const float* gb,
                                                   const float* ps, const float* pb,
                                                   const float* sc, const float* bi,
                                                   const float* steps, float* fs, float* fb,
                                                   int L, int D) {
  int d = blockIdx.x * 256 + threadIdx.x;
  int seg = blockIdx.y, b = blockIdx.z;
  const int SEGL = L / 16;
  float ss = steps[3];
  float rs_ = 0.f, rb_ = 0.f;
  for (int s = 0; s < seg; s++) {
    size_t pi = ((size_t)b * 16 + s) * D + d;
    rs_ += ps[pi]; rb_ += pb[pi];
  }
  float s0 = sc[d], b0 = bi[d];
  size_t base = ((size_t)b * L + seg * SEGL) * D + d;
  for (int i = 0; i < SEGL; i++) {
    size_t g = base + (size_t)i * D;
    fs[g] = s0 - ss * rs_;
    fb[g] = b0 - ss * rb_;
    rs_ += gs[g]; rb_ += gb[g];
  }
}

// ---------- orchestration ----------
extern "C" void kernel_launch(void* const* d_in, const int* in_sizes, int n_in, void* d_out,
                              int out_size, void* d_ws, size_t ws_size, hipStream_t stream) {
  const float* x        = (const float*)d_in[0];
  const float* labels   = (const float*)d_in[1];
  const float* weights  = (const float*)d_in[2];
  const float* W1       = (const float*)d_in[3];
  const float* b1       = (const float*)d_in[4];
  const float* W2       = (const float*)d_in[5];
  const float* b2       = (const float*)d_in[6];
  const float* ln_scale = (const float*)d_in[7];
  const float* ln_bias  = (const float*)d_in[8];
  const float* Wu       = (const float*)d_in[9];
  const float* bu       = (const float*)d_in[10];
  const float* steps    = (const float*)d_in[11];

  const int BL = in_sizes[2];   // 4096
  const int D  = in_sizes[7];   // 1024
  const int F  = in_sizes[4];   // 4096
  const int V  = in_sizes[10];  // 8192
  const int Bb = 2, L = BL / Bb;
  const int T2t = (L / 256) * (L / 256 + 1) / 2;   // 36 live 256-tri tiles
  const unsigned SMEM = 4 * 8192 * 2 * 2;          // 128 KB dynamic LDS

  char* ws = (char*)d_ws;
  size_t off = 0;
  auto take = [&](size_t b) { char* p = ws + off; off = (off + b + 255) & ~(size_t)255; return p; };

  ushort_t* xb   = (ushort_t*)take((size_t)BL * D * 2);
  ushort_t* w1t  = (ushort_t*)take((size_t)F * D * 2);
  ushort_t* w2t  = (ushort_t*)take((size_t)D * F * 2);
  ushort_t* w2b  = (ushort_t*)take((size_t)F * D * 2);
  ushort_t* wut  = (ushort_t*)take((size_t)V * D * 2);
  ushort_t* wub  = (ushort_t*)take((size_t)D * V * 2);
  ushort_t* H1b  = (ushort_t*)take((size_t)BL * F * 2);
  ushort_t* H2b  = (ushort_t*)take((size_t)BL * F * 2);
  float*    nbuf = (float*)take((size_t)BL * D * 4);
  float*    rstd = (float*)take((size_t)BL * 4);
  ushort_t* h4b  = (ushort_t*)take((size_t)BL * D * 2);
  float*    wsumb= (float*)take(256);
  float*    G4   = (float*)take((size_t)BL * D * 4);   // also g_bias
  float*    gsc  = (float*)take((size_t)BL * D * 4);   // g_scale
  ushort_t* g3b  = (ushort_t*)take((size_t)BL * D * 2);
  ushort_t* g3t  = (ushort_t*)take((size_t)BL * D * 2);
  float*    fs   = (float*)take((size_t)BL * D * 4);
  float*    fb   = (float*)take((size_t)BL * D * 4);
  ushort_t* x4b  = (ushort_t*)take((size_t)BL * D * 2);
  float*    psc  = (float*)take((size_t)Bb * 16 * D * 4);
  float*    pbi  = (float*)take((size_t)Bb * 16 * D * 4);
  // poolA (134MB), time-multiplexed (liveness audited):
  //  step2 H3 partials [0,67) -> step4 logitsb [0,64) -> step6 G4 partials [0,67)
  //  -> step8 g1b [0,32), step9 g1t [32,64) -> step10 S1b [64,80)
  //  -> step11 x2b [96,128) -> step12 X3 partials [0,67) (g1*/S1b dead)
  //  -> step14 x3 out [72,89) (reads X3 partials [0,67), x2b dead)
  char* poolA = take((size_t)BL * V * 4);
  ushort_t* logitsb = (ushort_t*)poolA;
  float*    partA  = (float*)poolA;
  ushort_t* g1b = (ushort_t*)poolA;
  ushort_t* g1t = (ushort_t*)(poolA + (size_t)BL * F * 2);
  ushort_t* S1b = (ushort_t*)(poolA + (size_t)BL * F * 4);
  ushort_t* x2b = (ushort_t*)(poolA + 96ull * 1024 * 1024);
  float*    x3  = (float*)(poolA + 72ull * 1024 * 1024);
  // poolB (64MB): dlb [0,64) -> S1 partials [0,38) -> S2 partials [0,38),
  // S2b [40,56)
  char* poolB = take((size_t)BL * V * 2);
  ushort_t* dlb = (ushort_t*)poolB;
  float*    partT2 = (float*)poolB;
  ushort_t* S2b = (ushort_t*)(poolB + 40ull * 1024 * 1024);

  dim3 blk(256), blk5(512);
  const size_t MN_D = (size_t)BL * D;

  k_conv<<<dim3((unsigned)((size_t)BL * D / 1024)), blk, 0, stream>>>(x, xb, (size_t)BL * D);
  k_tconv<<<dim3(F / 32, D / 32), blk, 0, stream>>>(W1, w1t, D, F);
  k_wprep<<<dim3(D / 32, F / 32), blk, 0, stream>>>(W2, w2b, w2t, F, D);   // straight + (D,F)T
  k_wprep<<<dim3(V / 32, D / 32), blk, 0, stream>>>(Wu, wub, wut, D, V);   // straight + (V,D)T

  GemmP p;
  auto clr = [&]() { p = GemmP{}; };

  // 1) H1b = bf16(x@W1+b1) ; H2b = bf16(relu^2)
  clr(); p.A = xb; p.B = w1t; p.M = BL; p.N = F; p.K = D;
  p.outb = H1b; p.outb2 = H2b; p.bias = b1;
  gemm256<1><<<dim3(F / 256, BL / 256, 1), blk5, SMEM, stream>>>(p);
  // 2) H3 partials [split-K 4] -> fused combine+LN fwd
  clr(); p.A = H2b; p.B = w2t; p.M = BL; p.N = D; p.K = F;
  p.part = partA; p.ksplit = 4; p.Kc = F / 4;
  gemm256<6><<<dim3(D / 256, BL / 256, 4), blk5, SMEM, stream>>>(p);
  k_lncomb<<<dim3(BL), blk, 0, stream>>>(partA, b2, ln_scale, ln_bias, nbuf, rstd, h4b, MN_D, D, 4);
  // 4) logits = bf16(h4@Wu + bu)
  clr(); p.A = h4b; p.B = wut; p.M = BL; p.N = V; p.K = D; p.outb = logitsb; p.bias = bu;
  gemm256<8><<<dim3(V / 256, BL / 256, 1), blk5, SMEM, stream>>>(p);
  // 5) fused softmax grad
  k_wsum<<<dim3(1), blk, 0, stream>>>(weights, wsumb, BL);
  k_softgrad<<<dim3(BL), blk, 0, stream>>>(logitsb, labels, weights, wsumb, dlb, V);
  // 6) G4 partials [split-K 4] -> fused combine+LN bwd
  clr(); p.A = dlb; p.B = wub; p.M = BL; p.N = D; p.K = V;
  p.part = partA; p.ksplit = 4; p.Kc = V / 4;
  gemm256<6><<<dim3(D / 256, BL / 256, 4), blk5, SMEM, stream>>>(p);
  k_lnbwdc<<<dim3(BL), blk, 0, stream>>>(partA, MN_D, 4, nbuf, rstd, ln_scale, g3b, gsc, G4, D);
  // 8) g1 = (g3 @ W2^T) * 2*sqrt(H2)
  clr(); p.A = g3b; p.B = w2b; p.M = BL; p.N = F; p.K = D; p.outb = g1b; p.auxb = H2b;
  gemm256<2><<<dim3(F / 256, BL / 256, 1), blk5, SMEM, stream>>>(p);
  // 9) transposes for attention V-operands
  k_tb2b<<<dim3(F / 32, L / 32, Bb), blk, 0, stream>>>(g1b, g1t, L, F);
  k_tb2b<<<dim3(D / 32, L / 32, Bb), blk, 0, stream>>>(g3b, g3t, L, D);
  // 10) S1 = tril(x x^T, -1)   [split-K 2, compact-tri, partials in poolB]
  clr(); p.A = xb; p.B = xb; p.M = L; p.N = L; p.K = D;
  p.sA = (long long)L * D; p.sB = (long long)L * D;
  p.part = partT2; p.ksplit = 2; p.Kc = D / 2; p.Tt = T2t;
  gemm256<7><<<dim3(T2t, 1, Bb * 2), blk5, SMEM, stream>>>(p);
  k_combtri<<<dim3(T2t, Bb), blk, 0, stream>>>(partT2, S1b, T2t, 2, L);
  // 11) x2 = relu(H1 - ss0 * S1@g1)^2   [K-limited, aux = bf16 H1b]
  clr(); p.A = S1b; p.B = g1t; p.M = L; p.N = F; p.K = L;
  p.sA = (long long)L * L; p.sB = (long long)F * L;
  p.outb = x2b; p.sOutB = (long long)L * F; p.auxb = H1b; p.sAuxF = (long long)L * F;
  p.steps = steps;
  gemm256<4><<<dim3(F / 256, L / 256, Bb), blk5, SMEM, stream>>>(p);
  // 12) X3 partials [split-K 4] (combine fused into step 14)
  clr(); p.A = x2b; p.B = w2t; p.M = BL; p.N = D; p.K = F;
  p.part = partA; p.ksplit = 4; p.Kc = F / 4;
  gemm256<6><<<dim3(D / 256, BL / 256, 4), blk5, SMEM, stream>>>(p);
  // 13) S2 = tril(x2 H2^T, -1)   [split-K 2, compact-tri, partials in poolB]
  clr(); p.A = x2b; p.B = H2b; p.M = L; p.N = L; p.K = F;
  p.sA = (long long)L * F; p.sB = (long long)L * F;
  p.part = partT2; p.ksplit = 2; p.Kc = F / 2; p.Tt = T2t;
  gemm256<7><<<dim3(T2t, 1, Bb * 2), blk5, SMEM, stream>>>(p);
  k_combtri<<<dim3(T2t, Bb), blk, 0, stream>>>(partT2, S2b, T2t, 2, L);
  // 14) x3 = (sum X3-partials + b2) - ss2 * S2@g3   [K-limited, fused combine]
  clr(); p.A = S2b; p.B = g3t; p.M = L; p.N = D; p.K = L;
  p.sA = (long long)L * L; p.sB = (long long)D * L;
  p.outf = x3; p.sOutF = (long long)L * D;
  p.part = partA; p.ksplit = 4; p.sAuxF = (long long)MN_D; p.bias = b2; p.steps = steps;
  gemm_bt<5><<<dim3(D / 128, L / 128, Bb), blk, 0, stream>>>(p);
  // 15) exclusive cumsums -> fast_scale / fast_bias
  k_scanpart<<<dim3(D / 256, 16, Bb), blk, 0, stream>>>(gsc, G4, psc, pbi, L, D);
  k_scanapply<<<dim3(D / 256, 16, Bb), blk, 0, stream>>>(gsc, G4, psc, pbi, ln_scale, ln_bias,
                                                         steps, fs, fb, L, D);
  // 16) x4 = LN(x3)*fast_scale + fast_bias
  k_lnfwd2<<<dim3(BL), blk, 0, stream>>>(x3, fs, fb, x4b, D);
  // 17) out = x4@Wu + bu   [nontemporal f32 stores]
  clr(); p.A = x4b; p.B = wut; p.M = BL; p.N = V; p.K = D; p.outf = (float*)d_out; p.bias = bu;
  gemm256<0><<<dim3(V / 256, BL / 256, 1), blk5, SMEM, stream>>>(p);
}